// Round 1
// baseline (79666.089 us; speedup 1.0000x reference)
//
#include <hip/hip_runtime.h>
#include <hip/hip_bf16.h>

// ---------------------------------------------------------------------------
// BayesianFilter: graph-GRU recurrent net.
// Key trick: gconv(xe_t) is linear in x_t, so edge aggregation is done ONCE in
// C-space (16 dims) for all t (k_agg), and the fused weight W_eg = W_enc@W_gX
// turns the per-step gconv into a row-local 16->64 matmul. After that the
// whole recurrence is row-parallel: one persistent kernel, no grid syncs.
//
// Round 3: 1024-thread mega blocks (64 rows/block). The 74KB of LDS weights
// is identical across blocks; sharing one copy across 4x the rows gives
// grid=256 (1 block/CU, ONE generation of the 299-step chain instead of two),
// 16 waves/CU instead of 8, and 4x fewer barriers per row of work. Inner
// per-thread math unchanged (rows rb+16j instead of rb+4j). Also: 1-step
// register prefetch of the aggT slice to hide its HBM latency under compute.
// ---------------------------------------------------------------------------

typedef unsigned short u16;

constexpr int N_ = 8, V_ = 2048, C_ = 16, T_ = 150, L_ = 64, E_ = 32768;
constexpr int NV_ = N_ * V_;             // 16384 rows
constexpr int CT_ = C_ * T_;             // 2400
constexpr int BR_ = 64;                  // rows per mega block
constexpr int TH_ = 1024;                // mega block threads

// ---- workspace layout (bytes) ----
constexpr size_t SZ_AGGT   = (size_t)T_ * N_ * V_ * C_ * 2;     // 78,643,200 bf16
constexpr size_t OFF_AGGT  = 0;
constexpr size_t OFF_COUNTS= OFF_AGGT + SZ_AGGT;                // int[V]
constexpr size_t OFF_S     = OFF_COUNTS + 8192;                 // float[V]
constexpr size_t OFF_RP    = OFF_S + 8192;                      // int[V+1] (pad)
constexpr size_t OFF_CUR   = OFF_RP + 8448;                     // int[V]
constexpr size_t OFF_CSRC  = OFF_CUR + 8192;                    // int[E]
constexpr size_t OFF_CATT  = OFF_CSRC + 131072;                 // float[E]
constexpr size_t OFF_WEGA  = OFF_CATT + 131072;                 // bf16[16][64]
constexpr size_t OFF_WEGB  = OFF_WEGA + 2048;
constexpr size_t OFF_BEGA  = OFF_WEGB + 2048;                   // float[64]
constexpr size_t OFF_BEGB  = OFF_BEGA + 256;
constexpr size_t OFF_FLAG  = OFF_BEGB + 256;                    // int dtype flag
constexpr size_t OFF_STAGE = OFF_FLAG + 256;                    // bf16 [T][NV][C]
constexpr size_t NEED_STAGE= OFF_STAGE + SZ_AGGT;               // ~157.6 MB

// ---- mega-kernel LDS layout (bytes). pitches chosen for <=2-way banks ----
constexpr int PITCH = 68;   // ushorts; row stride 136B -> bank stride 34 -> 2-way
constexpr int PEG   = 20;   // ushorts; 40B -> 10 dwords -> ~4-way worst case
constexpr int L_WIT = 0;                  // [192][68] bf16 = 26112
constexpr int L_WHT = 26112;              // 26112
constexpr int L_W1H = 52224;              // [64][68]  = 8704
constexpr int L_W2  = 60928;              // 8704
constexpr int L_WDEC= 69632;              // [16][68]  = 2176
constexpr int L_WEG = 71808;              // [64][20]  = 2560
constexpr int L_FB  = 74368;              // float[336] (pad to 75776)
constexpr int L_H   = 75776;              // bf16[64][64] = 8192
constexpr int L_M   = 83968;              // 8192
constexpr int L_AGG = 92160;              // bf16[64][16] = 2048
constexpr int L_S   = 94208;              // float[64]
constexpr int LDS_MEGA = 94464;           // <= 160KB -> 1 block/CU, 16 waves

#define DEVI __device__ __forceinline__

DEVI float bf2f(u16 u) {
    unsigned int v = ((unsigned int)u) << 16;
    float f; __builtin_memcpy(&f, &v, 4); return f;
}
DEVI u16 f2bf(float f) {   // round-to-nearest-even
    unsigned int v; __builtin_memcpy(&v, &f, 4);
    unsigned int r = (v + 0x7fffu + ((v >> 16) & 1u)) >> 16;
    return (u16)r;
}
// dtype-flag-aware scalar load: element i of a float32 OR bf16 buffer
DEVI float ldf(const void* p, size_t i, int f32) {
    return f32 ? ((const float*)p)[i] : bf2f(((const u16*)p)[i]);
}
DEVI float4 bf4(const u16* p) {
    ushort4 u = *reinterpret_cast<const ushort4*>(p);
    return make_float4(bf2f(u.x), bf2f(u.y), bf2f(u.z), bf2f(u.w));
}
DEVI float dot4(float4 a, float4 b) {
    return a.x*b.x + a.y*b.y + a.z*b.z + a.w*b.w;
}
DEVI float sigm(float v) { return 1.f / (1.f + __expf(-v)); }
DEVI float tanh_(float v) {   // overflow-safe tanh via exp of -2|x|
    float a = fabsf(v);
    float e = __expf(-2.f * a);
    float t = (1.f - e) / (1.f + e);
    return v < 0.f ? -t : t;
}

// transposed weight loads into LDS: dst[o*pitch + k] = src[k*O + o]
DEVI void loadT64(u16* dst, const void* src, int O, int pitch, int f32) {
    for (int i = threadIdx.x; i < 64 * O; i += TH_) {
        int o = i >> 6, k = i & 63;
        dst[o * pitch + k] = f2bf(ldf(src, (size_t)k * O + o, f32));
    }
}
DEVI void loadT16(u16* dst, const void* src, int O, int pitch, int f32) {
    for (int i = threadIdx.x; i < 16 * O; i += TH_) {
        int o = i >> 4, k = i & 15;
        dst[o * pitch + k] = f2bf(ldf(src, (size_t)k * O + o, f32));
    }
}
DEVI void loadBias(float* dst, const void* src, int n, int f32) {
    for (int i = threadIdx.x; i < n; i += TH_) dst[i] = ldf(src, i, f32);
}

// out[64 x 64] += act[64 x 64] @ W[64 x 64]   (WT layout [o][k], thread: 4 rows)
DEVI void gemm64(const u16* WT, const u16* act, int l, int rb,
                 const float init[4], float out[4]) {
    const u16* w  = WT + l * PITCH;
    const u16* a0 = act + (rb +  0) * 64;
    const u16* a1 = act + (rb + 16) * 64;
    const u16* a2 = act + (rb + 32) * 64;
    const u16* a3 = act + (rb + 48) * 64;
    float o0 = init[0], o1 = init[1], o2 = init[2], o3 = init[3];
#pragma unroll
    for (int k4 = 0; k4 < 16; ++k4) {
        float4 wv = bf4(w + 4 * k4);
        o0 += dot4(bf4(a0 + 4 * k4), wv);
        o1 += dot4(bf4(a1 + 4 * k4), wv);
        o2 += dot4(bf4(a2 + 4 * k4), wv);
        o3 += dot4(bf4(a3 + 4 * k4), wv);
    }
    out[0] = o0; out[1] = o1; out[2] = o2; out[3] = o3;
}

// fused GRU gate GEMMs: gi = m@Wi + b, gh = h@Wh ; z/r summed, n parts separate
DEVI void gruGemm(const u16* WiT, const u16* WhT, const u16* mS, const u16* hS,
                  int l, int rb, const float* bg,
                  float az[4], float ar[4], float ani[4], float anh[4]) {
#pragma unroll
    for (int j = 0; j < 4; ++j) {
        az[j] = bg[l]; ar[j] = bg[64 + l]; ani[j] = bg[128 + l]; anh[j] = 0.f;
    }
    const u16* wz = WiT + (  0 + l) * PITCH;
    const u16* wr = WiT + ( 64 + l) * PITCH;
    const u16* wn = WiT + (128 + l) * PITCH;
    const u16* vz = WhT + (  0 + l) * PITCH;
    const u16* vr = WhT + ( 64 + l) * PITCH;
    const u16* vn = WhT + (128 + l) * PITCH;
#pragma unroll
    for (int k4 = 0; k4 < 16; ++k4) {
        float4 a = bf4(wz + 4*k4), b = bf4(wr + 4*k4), c = bf4(wn + 4*k4);
        float4 d = bf4(vz + 4*k4), e = bf4(vr + 4*k4), f = bf4(vn + 4*k4);
#pragma unroll
        for (int j = 0; j < 4; ++j) {
            int r = rb + 16 * j;
            float4 mm = bf4(mS + r * 64 + 4 * k4);
            float4 hh = bf4(hS + r * 64 + 4 * k4);
            az[j]  += dot4(mm, a) + dot4(hh, d);
            ar[j]  += dot4(mm, b) + dot4(hh, e);
            ani[j] += dot4(mm, c);
            anh[j] += dot4(hh, f);
        }
    }
}

// m = agg_c @ W_eg + S * b_eg  -> mS (bf16)
DEVI void mcalc(const u16* WegT, const u16* aggS, const float* beg,
                const float* Sl, int l, int rb, u16* mS) {
    const u16* w = WegT + l * PEG;
    float4 w0 = bf4(w), w1 = bf4(w + 4), w2 = bf4(w + 8), w3 = bf4(w + 12);
#pragma unroll
    for (int j = 0; j < 4; ++j) {
        int r = rb + 16 * j;
        float acc = Sl[r] * beg[l];
        acc += dot4(bf4(aggS + r*16     ), w0) + dot4(bf4(aggS + r*16 +  4), w1)
             + dot4(bf4(aggS + r*16 +  8), w2) + dot4(bf4(aggS + r*16 + 12), w3);
        mS[r * 64 + l] = f2bf(acc);
    }
}

DEVI void decodeStore(const u16* WdT, const u16* hS, const float* bd,
                      int rg, int cg, void* outp, int staged, int isf32,
                      int base, int t) {
    float acc = bd[cg];
    const u16* w = WdT + cg * PITCH;
    const u16* a = hS + rg * 64;
#pragma unroll
    for (int k4 = 0; k4 < 16; ++k4) acc += dot4(bf4(w + 4*k4), bf4(a + 4*k4));
    if (staged) {
        ((u16*)outp)[((size_t)t * NV_ + base + rg) * C_ + cg] = f2bf(acc);
    } else {
        size_t off = (size_t)(base + rg) * CT_ + (size_t)cg * T_ + t;
        if (isf32) ((float*)outp)[off] = acc;
        else       ((u16*)outp)[off] = f2bf(acc);
    }
}

// ---------------------------------------------------------------------------
// dtype detection: interpret first 1024 u16 of x as bf16. True bf16 N(0,1)
// data has exponent field <= ~0x81. f32 data misread as bf16 gives ~40% of
// the low-half u16s an exponent >= 0x9A (|v| >= 2^27). Count >= 8 -> f32.
// ---------------------------------------------------------------------------
__global__ void k_detect(const u16* __restrict__ x, int* __restrict__ flag) {
    __shared__ int cnt;
    if (threadIdx.x == 0) cnt = 0;
    __syncthreads();
    int local = 0;
#pragma unroll
    for (int j = 0; j < 4; ++j) {
        u16 u = x[threadIdx.x * 4 + j];
        int ex = (u >> 7) & 0xFF;
        if (ex >= 0x9A) ++local;
    }
    if (local) atomicAdd(&cnt, local);
    __syncthreads();
    if (threadIdx.x == 0) *flag = (cnt >= 8) ? 1 : 0;
}

// ---------------------------------------------------------------------------
// CSR build
// ---------------------------------------------------------------------------
__global__ void k_count(const int* __restrict__ ei, const void* __restrict__ eattr,
                        const int* __restrict__ flag,
                        int* __restrict__ counts, float* __restrict__ S) {
    int f32 = *flag;
    int e = blockIdx.x * 256 + threadIdx.x;
    if (e < E_) {
        int dst = ei[E_ + e];
        atomicAdd(&counts[dst], 1);
        atomicAdd(&S[dst], ldf(eattr, e, f32));
    }
}

__global__ void k_scan(const int* __restrict__ counts, int* __restrict__ row_ptr,
                       int* __restrict__ cursor) {
    __shared__ int lds[256];
    int tid = threadIdx.x;
    int base = tid * 8, loc[8], s = 0;
#pragma unroll
    for (int i = 0; i < 8; ++i) { loc[i] = s; s += counts[base + i]; }
    lds[tid] = s; __syncthreads();
    for (int d = 1; d < 256; d <<= 1) {
        int v = (tid >= d) ? lds[tid - d] : 0;
        __syncthreads();
        lds[tid] += v;
        __syncthreads();
    }
    int off = (tid == 0) ? 0 : lds[tid - 1];
#pragma unroll
    for (int i = 0; i < 8; ++i) {
        int rp = off + loc[i];
        row_ptr[base + i] = rp; cursor[base + i] = rp;
    }
    if (tid == 255) row_ptr[V_] = lds[255];
}

__global__ void k_fill(const int* __restrict__ ei, const void* __restrict__ eattr,
                       const int* __restrict__ flag,
                       int* __restrict__ cursor, int* __restrict__ col_src,
                       float* __restrict__ col_att) {
    int f32 = *flag;
    int e = blockIdx.x * 256 + threadIdx.x;
    if (e < E_) {
        int dst = ei[E_ + e];
        int pos = atomicAdd(&cursor[dst], 1);
        col_src[pos] = ei[e];
        col_att[pos] = ldf(eattr, e, f32);
    }
}

// fused weights: W_egX = W_enc @ W_gX ; b_egX = b_enc @ W_gX
__global__ void k_wprep(const void* __restrict__ W_enc, const void* __restrict__ b_enc,
                        const void* __restrict__ W_gd, const void* __restrict__ W_gc,
                        const int* __restrict__ flag,
                        u16* __restrict__ wegA, u16* __restrict__ wegB,
                        float* __restrict__ begA, float* __restrict__ begB) {
    int f32 = *flag;
    int tid = threadIdx.x;
    for (int idx = tid; idx < 1024; idx += 256) {
        int c = idx >> 6, l = idx & 63;
        float sa = 0.f, sb = 0.f;
        for (int k = 0; k < 64; ++k) {
            float we = ldf(W_enc, c * 64 + k, f32);
            sa += we * ldf(W_gd, k * 64 + l, f32);
            sb += we * ldf(W_gc, k * 64 + l, f32);
        }
        wegA[idx] = f2bf(sa); wegB[idx] = f2bf(sb);
    }
    if (tid < 64) {
        float sa = 0.f, sb = 0.f;
        for (int k = 0; k < 64; ++k) {
            float be = ldf(b_enc, k, f32);
            sa += be * ldf(W_gd, k * 64 + tid, f32);
            sb += be * ldf(W_gc, k * 64 + tid, f32);
        }
        begA[tid] = sa; begB[tid] = sb;
    }
}

// ---------------------------------------------------------------------------
// pre-aggregation: aggT[t][n][v][c] = sum_{e: dst=v} attr_e * x[n, src_e, c, t]
// block = (n, 4 dst nodes); x rows are contiguous (c,t) slabs -> coalesced.
// ---------------------------------------------------------------------------
__global__ __launch_bounds__(256) void k_agg(
    const void* __restrict__ x, const int* __restrict__ flag,
    const int* __restrict__ row_ptr,
    const int* __restrict__ col_src, const float* __restrict__ col_att,
    u16* __restrict__ aggT) {
    __shared__ float lbuf[4 * CT_];   // 38,400 B
    int f32 = *flag;
    int tid = threadIdx.x;
    int n  = blockIdx.x >> 9;
    int v0 = (blockIdx.x & 511) * 4;
    for (int d = 0; d < 4; ++d) {
        int v = v0 + d;
        int e0 = row_ptr[v], e1 = row_ptr[v + 1];
        float acc[10];
#pragma unroll
        for (int k = 0; k < 10; ++k) acc[k] = 0.f;
        for (int e = e0; e < e1; ++e) {
            float a = col_att[e];
            size_t ro = (size_t)(n * V_ + col_src[e]) * CT_;
            if (f32) {
                const float* xr = (const float*)x + ro;
#pragma unroll
                for (int k = 0; k < 10; ++k) {
                    int idx = tid + 256 * k;
                    if (idx < CT_) acc[k] += a * xr[idx];
                }
            } else {
                const u16* xr = (const u16*)x + ro;
#pragma unroll
                for (int k = 0; k < 10; ++k) {
                    int idx = tid + 256 * k;
                    if (idx < CT_) acc[k] += a * bf2f(xr[idx]);
                }
            }
        }
#pragma unroll
        for (int k = 0; k < 10; ++k) {
            int idx = tid + 256 * k;
            if (idx < CT_) lbuf[d * CT_ + idx] = acc[k];
        }
    }
    __syncthreads();
    // write in [t][n][v][c] order (128B contiguous per t)
    for (int w = tid; w < 4 * CT_; w += 256) {
        int t = w >> 6, rem = w & 63, d = rem >> 4, c = rem & 15;
        aggT[((size_t)(t * N_ + n) * V_ + v0 + d) * C_ + c] =
            f2bf(lbuf[d * CT_ + c * T_ + t]);
    }
}

// ---------------------------------------------------------------------------
// mega kernel: phase A (domain GRU, 150 steps) -> dom MLP + zdterm ->
// phase B (ODE + GRU + decode, steps 1..149). 64 rows / block, all row-local.
// thread maps: (l = tid&63, rows rb+16j) for GEMMs; (rg = tid>>4, cg = tid&15)
// for agg/x0/decode. 1024 threads, 1 block/CU, grid = 256 = one generation.
// ---------------------------------------------------------------------------
__global__ __launch_bounds__(TH_, 4) void k_mega(
    const void* __restrict__ x, const u16* __restrict__ aggT,
    const float* __restrict__ Sg, const int* __restrict__ flag,
    const void* __restrict__ W_enc, const void* __restrict__ b_enc,
    const void* __restrict__ gd_Wi, const void* __restrict__ gd_Wh, const void* __restrict__ gd_b,
    const void* __restrict__ W_dom1, const void* __restrict__ b_dom1,
    const void* __restrict__ W_dom2, const void* __restrict__ b_dom2,
    const void* __restrict__ ode_W1, const void* __restrict__ ode_b1,
    const void* __restrict__ ode_W2, const void* __restrict__ ode_b2,
    const void* __restrict__ gc_Wi, const void* __restrict__ gc_Wh, const void* __restrict__ gc_b,
    const void* __restrict__ W_dec, const void* __restrict__ b_dec,
    const u16* __restrict__ wegA, const u16* __restrict__ wegB,
    const float* __restrict__ begA, const float* __restrict__ begB,
    void* __restrict__ outp, int staged) {
    extern __shared__ char smem[];
    u16* WiT  = (u16*)(smem + L_WIT);
    u16* WhT  = (u16*)(smem + L_WHT);
    u16* W1hT = (u16*)(smem + L_W1H);
    u16* W2T  = (u16*)(smem + L_W2);
    u16* WdT  = (u16*)(smem + L_WDEC);
    u16* WegT = (u16*)(smem + L_WEG);
    float* fB = (float*)(smem + L_FB);    // [0..191] gate bias, [192..255] b_eg,
                                          // [256..319] ode_b2, [320..335] b_dec
    u16* hS   = (u16*)(smem + L_H);
    u16* mS   = (u16*)(smem + L_M);
    u16* aggS = (u16*)(smem + L_AGG);
    float* Sl = (float*)(smem + L_S);

    const int f32 = *flag;
    const int tid = threadIdx.x;
    const int l = tid & 63, rb = tid >> 6;      // rb 0..15 == wave id
    const int rg = tid >> 4, cg = tid & 15;     // rg 0..63
    const int base = blockIdx.x * BR_;
    const int n = base >> 11, v0 = base & 2047;

    // ---- phase A setup
    loadT64(WiT, gd_Wi, 192, PITCH, f32);
    loadT64(WhT, gd_Wh, 192, PITCH, f32);
    for (int i = tid; i < 16 * 64; i += TH_) {     // wegA already bf16
        int o = i >> 4, k = i & 15;
        WegT[o * PEG + k] = wegA[k * 64 + o];
    }
    loadBias(fB, gd_b, 192, f32);
    for (int i = tid; i < 64; i += TH_) fB[192 + i] = begA[i];
    if (tid < 64) Sl[tid] = Sg[v0 + tid];
    __syncthreads();

    float hd[4] = {0.f, 0.f, 0.f, 0.f};
    // prefetch t=0 agg slice (2KB contiguous)
    u16 pf = aggT[((size_t)(0 * N_ + n) * V_ + v0) * C_ + tid];
    for (int t = 0; t < T_; ++t) {
        aggS[tid] = pf;
        if (t + 1 < T_)
            pf = aggT[((size_t)((t + 1) * N_ + n) * V_ + v0) * C_ + tid];
#pragma unroll
        for (int j = 0; j < 4; ++j) hS[(rb + 16*j) * 64 + l] = f2bf(hd[j]);
        __syncthreads();
        mcalc(WegT, aggS, fB + 192, Sl, l, rb, mS);
        __syncthreads();
        float az[4], ar[4], ani[4], anh[4];
        gruGemm(WiT, WhT, mS, hS, l, rb, fB, az, ar, ani, anh);
#pragma unroll
        for (int j = 0; j < 4; ++j) {
            float z = sigm(az[j]);
            float r = sigm(ar[j]);
            float nn = tanh_(ani[j] + r * anh[j]);
            hd[j] = (1.f - z) * nn + z * hd[j];
        }
        __syncthreads();
    }

    // ---- domain MLP: z_D = tanh(hd@Wdom1+b1)@Wdom2+b2 ; zdterm = zD@W1[64:]+ode_b1
#pragma unroll
    for (int j = 0; j < 4; ++j) hS[(rb + 16*j) * 64 + l] = f2bf(hd[j]);
    loadT64(W1hT, W_dom1, 64, PITCH, f32);
    loadT64(W2T,  W_dom2, 64, PITCH, f32);
    loadT64(WiT,  (const void*)((const char*)ode_W1 + (size_t)64 * 64 * (f32 ? 4 : 2)),
            64, PITCH, f32);   // zD half of ode_W1
    loadBias(fB,       b_dom1, 64, f32);
    loadBias(fB + 64,  b_dom2, 64, f32);
    loadBias(fB + 128, ode_b1, 64, f32);
    __syncthreads();
    float init4[4], tmp4[4];
#pragma unroll
    for (int j = 0; j < 4; ++j) init4[j] = fB[l];
    gemm64(W1hT, hS, l, rb, init4, tmp4);
#pragma unroll
    for (int j = 0; j < 4; ++j) mS[(rb + 16*j) * 64 + l] = f2bf(tanh_(tmp4[j]));
    __syncthreads();
    float zD[4];
#pragma unroll
    for (int j = 0; j < 4; ++j) init4[j] = fB[64 + l];
    gemm64(W2T, mS, l, rb, init4, zD);
    __syncthreads();
#pragma unroll
    for (int j = 0; j < 4; ++j) hS[(rb + 16*j) * 64 + l] = f2bf(zD[j]);
    __syncthreads();
    float zt[4];
#pragma unroll
    for (int j = 0; j < 4; ++j) init4[j] = fB[128 + l];
    gemm64(WiT, hS, l, rb, init4, zt);
    __syncthreads();

    // ---- phase B setup
    loadT64(WiT, gc_Wi, 192, PITCH, f32);
    loadT64(WhT, gc_Wh, 192, PITCH, f32);
    loadT64(W1hT, ode_W1, 64, PITCH, f32);   // h half
    loadT64(W2T,  ode_W2, 64, PITCH, f32);
    loadT64(WdT,  W_dec, 16, PITCH, f32);
    loadT16(WegT, W_enc, 64, PEG, f32);      // raw W_enc for h0
    loadBias(fB, b_enc, 64, f32);
    loadBias(fB + 256, ode_b2, 64, f32);
    loadBias(fB + 320, b_dec, 16, f32);
    for (int i = tid; i < 64; i += TH_) fB[192 + i] = begB[i];
    __syncthreads();
    // h0 = x[:,:,:,0] @ W_enc + b_enc
    aggS[tid] = f2bf(ldf(x, (size_t)(base + rg) * CT_ + (size_t)cg * T_, f32));
    __syncthreads();
    float h[4];
    {
        const u16* w = WegT + l * PEG;
        float4 w0 = bf4(w), w1 = bf4(w+4), w2 = bf4(w+8), w3 = bf4(w+12);
#pragma unroll
        for (int j = 0; j < 4; ++j) {
            int r = rb + 16 * j;
            float acc = fB[l];
            acc += dot4(bf4(aggS + r*16), w0) + dot4(bf4(aggS + r*16 + 4), w1)
                 + dot4(bf4(aggS + r*16 + 8), w2) + dot4(bf4(aggS + r*16 + 12), w3);
            h[j] = acc;
            hS[r * 64 + l] = f2bf(acc);
        }
    }
    __syncthreads();
    decodeStore(WdT, hS, fB + 320, rg, cg, outp, staged, f32, base, 0);
    for (int i = tid; i < 16 * 64; i += TH_) {     // wegB already bf16
        int o = i >> 4, k = i & 15;
        WegT[o * PEG + k] = wegB[k * 64 + o];
    }
    loadBias(fB, gc_b, 192, f32);
    __syncthreads();

    // prefetch t=1 agg slice
    pf = aggT[((size_t)(1 * N_ + n) * V_ + v0) * C_ + tid];
    for (int t = 1; t < T_; ++t) {
        // s1: agg stage (prefetched) + ODE hidden u = tanh(h@W1h + zdterm)
        aggS[tid] = pf;
        if (t + 1 < T_)
            pf = aggT[((size_t)((t + 1) * N_ + n) * V_ + v0) * C_ + tid];
        float u[4];
        gemm64(W1hT, hS, l, rb, zt, u);
#pragma unroll
        for (int j = 0; j < 4; ++j) mS[(rb + 16*j) * 64 + l] = f2bf(tanh_(u[j]));
        __syncthreads();
        // s2: dh = u@W2 + b2 ; h_ode = h + dh
        float dh[4];
#pragma unroll
        for (int j = 0; j < 4; ++j) init4[j] = fB[256 + l];
        gemm64(W2T, mS, l, rb, init4, dh);
        float ho[4];
#pragma unroll
        for (int j = 0; j < 4; ++j) ho[j] = h[j] + dh[j];
        __syncthreads();
        // s3: stage h_ode ; m = agg@W_eg + S*b_eg
#pragma unroll
        for (int j = 0; j < 4; ++j) hS[(rb + 16*j) * 64 + l] = f2bf(ho[j]);
        mcalc(WegT, aggS, fB + 192, Sl, l, rb, mS);
        __syncthreads();
        // s4: GRU(m, h_ode)
        float az[4], ar[4], ani[4], anh[4];
        gruGemm(WiT, WhT, mS, hS, l, rb, fB, az, ar, ani, anh);
#pragma unroll
        for (int j = 0; j < 4; ++j) {
            float z = sigm(az[j]);
            float r = sigm(ar[j]);
            float nn = tanh_(ani[j] + r * anh[j]);
            h[j] = (1.f - z) * nn + z * ho[j];
        }
        __syncthreads();
        // s5: stage h_new, decode
#pragma unroll
        for (int j = 0; j < 4; ++j) hS[(rb + 16*j) * 64 + l] = f2bf(h[j]);
        __syncthreads();
        decodeStore(WdT, hS, fB + 320, rg, cg, outp, staged, f32, base, t);
    }
}

// de-transpose staged output [t][row][c] -> d_out [row][c][t]
__global__ __launch_bounds__(256) void k_detrans(const u16* __restrict__ stage,
                                                 const int* __restrict__ flag,
                                                 void* __restrict__ out) {
    __shared__ u16 lt[8 * CT_];   // 38,400 B
    int f32 = *flag;
    int tid = threadIdx.x;
    int base = blockIdx.x * 8;
    int r = tid >> 4, c = tid & 15;
    for (int t = 0; t < T_; ++t) {
        if (tid < 128)
            lt[r * CT_ + c * T_ + t] = stage[((size_t)t * NV_ + base + r) * C_ + c];
    }
    __syncthreads();
    size_t ob = (size_t)base * CT_;
    if (f32) {
        float* o = (float*)out;
        for (int i = tid; i < 8 * CT_; i += 256) o[ob + i] = bf2f(lt[i]);
    } else {
        u16* o = (u16*)out;
        for (int i = tid; i < 8 * CT_; i += 256) o[ob + i] = lt[i];
    }
}

// ---------------------------------------------------------------------------
extern "C" void kernel_launch(void* const* d_in, const int* in_sizes, int n_in,
                              void* d_out, int out_size, void* d_ws, size_t ws_size,
                              hipStream_t stream) {
    const void* x      = d_in[0];
    const int*  ei     = (const int*)d_in[1];
    const void* eattr  = d_in[2];
    const void* W_enc  = d_in[3];
    const void* b_enc  = d_in[4];
    const void* W_gd   = d_in[5];
    const void* gd_Wi  = d_in[6];
    const void* gd_Wh  = d_in[7];
    const void* gd_b   = d_in[8];
    const void* W_dom1 = d_in[9];
    const void* b_dom1 = d_in[10];
    const void* W_dom2 = d_in[11];
    const void* b_dom2 = d_in[12];
    const void* ode_W1 = d_in[13];
    const void* ode_b1 = d_in[14];
    const void* ode_W2 = d_in[15];
    const void* ode_b2 = d_in[16];
    const void* W_gc   = d_in[17];
    const void* gc_Wi  = d_in[18];
    const void* gc_Wh  = d_in[19];
    const void* gc_b   = d_in[20];
    const void* W_dec  = d_in[21];
    const void* b_dec  = d_in[22];

    char* ws = (char*)d_ws;
    u16*   aggT    = (u16*)  (ws + OFF_AGGT);
    int*   counts  = (int*)  (ws + OFF_COUNTS);
    float* S       = (float*)(ws + OFF_S);
    int*   row_ptr = (int*)  (ws + OFF_RP);
    int*   cursor  = (int*)  (ws + OFF_CUR);
    int*   col_src = (int*)  (ws + OFF_CSRC);
    float* col_att = (float*)(ws + OFF_CATT);
    u16*   wegA    = (u16*)  (ws + OFF_WEGA);
    u16*   wegB    = (u16*)  (ws + OFF_WEGB);
    float* begA    = (float*)(ws + OFF_BEGA);
    float* begB    = (float*)(ws + OFF_BEGB);
    int*   flag    = (int*)  (ws + OFF_FLAG);
    u16*   stage   = (u16*)  (ws + OFF_STAGE);

    int staged = (ws_size >= NEED_STAGE) ? 1 : 0;
    void* mega_out = staged ? (void*)stage : d_out;

    // allow >64KB dynamic LDS (no-op where not required); idempotent per call
    (void)hipFuncSetAttribute((const void*)k_mega,
                              hipFuncAttributeMaxDynamicSharedMemorySize, LDS_MEGA);

    hipLaunchKernelGGL(k_detect, dim3(1), dim3(256), 0, stream, (const u16*)x, flag);
    hipMemsetAsync(ws + OFF_COUNTS, 0, 16384, stream);  // counts + S
    hipLaunchKernelGGL(k_count, dim3(E_ / 256), dim3(256), 0, stream,
                       ei, eattr, flag, counts, S);
    hipLaunchKernelGGL(k_scan, dim3(1), dim3(256), 0, stream,
                       counts, row_ptr, cursor);
    hipLaunchKernelGGL(k_fill, dim3(E_ / 256), dim3(256), 0, stream,
                       ei, eattr, flag, cursor, col_src, col_att);
    hipLaunchKernelGGL(k_wprep, dim3(1), dim3(256), 0, stream,
                       W_enc, b_enc, W_gd, W_gc, flag, wegA, wegB, begA, begB);
    hipLaunchKernelGGL(k_agg, dim3(N_ * V_ / 4), dim3(256), 0, stream,
                       x, flag, row_ptr, col_src, col_att, aggT);
    hipLaunchKernelGGL(k_mega, dim3(NV_ / BR_), dim3(TH_), LDS_MEGA, stream,
                       x, aggT, S, flag, W_enc, b_enc, gd_Wi, gd_Wh, gd_b,
                       W_dom1, b_dom1, W_dom2, b_dom2,
                       ode_W1, ode_b1, ode_W2, ode_b2,
                       gc_Wi, gc_Wh, gc_b, W_dec, b_dec,
                       wegA, wegB, begA, begB, mega_out, staged);
    if (staged)
        hipLaunchKernelGGL(k_detrans, dim3(NV_ / 8), dim3(256), 0, stream,
                           stage, flag, d_out);
}

// Round 2
// 36483.801 us; speedup vs baseline: 2.1836x; 2.1836x over previous
//
#include <hip/hip_runtime.h>
#include <hip/hip_bf16.h>

// ---------------------------------------------------------------------------
// BayesianFilter: graph-GRU recurrent net.
// Key trick: gconv(xe_t) is linear in x_t, so edge aggregation is done ONCE in
// C-space (16 dims) for all t (k_agg), and the fused weight W_eg = W_enc@W_gX
// turns the per-step gconv into a row-local 16->64 matmul. After that the
// whole recurrence is row-parallel: one persistent kernel, no grid syncs.
//
// Round 4: spill elimination. Rounds 0/1 both ran at ~3.47 TB/s of HBM traffic
// (97 GB resp. 275 GB for a 0.24 GB algorithm) -> k_mega was scratch-spill
// bound. Cause: extern-shared LDS is invisible to the register allocator's
// occupancy heuristic, which clamped VGPRs to 128 (resp. 64) and spilled the
// unrolled gruGemm live ranges. Fix: amdgpu_waves_per_eu(2,2) pins the
// allocator to the occupancy LDS already dictates (2 blocks/CU, 8 waves/CU),
// giving a 256-VGPR budget -> no spill, zero occupancy cost. Structure is
// otherwise the verified round-0 kernel + 1-step aggT register prefetch.
// ---------------------------------------------------------------------------

typedef unsigned short u16;

constexpr int N_ = 8, V_ = 2048, C_ = 16, T_ = 150, L_ = 64, E_ = 32768;
constexpr int NV_ = N_ * V_;             // 16384 rows
constexpr int CT_ = C_ * T_;             // 2400

// ---- workspace layout (bytes) ----
constexpr size_t SZ_AGGT   = (size_t)T_ * N_ * V_ * C_ * 2;     // 78,643,200 bf16
constexpr size_t OFF_AGGT  = 0;
constexpr size_t OFF_COUNTS= OFF_AGGT + SZ_AGGT;                // int[V]
constexpr size_t OFF_S     = OFF_COUNTS + 8192;                 // float[V]
constexpr size_t OFF_RP    = OFF_S + 8192;                      // int[V+1] (pad)
constexpr size_t OFF_CUR   = OFF_RP + 8448;                     // int[V]
constexpr size_t OFF_CSRC  = OFF_CUR + 8192;                    // int[E]
constexpr size_t OFF_CATT  = OFF_CSRC + 131072;                 // float[E]
constexpr size_t OFF_WEGA  = OFF_CATT + 131072;                 // bf16[16][64]
constexpr size_t OFF_WEGB  = OFF_WEGA + 2048;
constexpr size_t OFF_BEGA  = OFF_WEGB + 2048;                   // float[64]
constexpr size_t OFF_BEGB  = OFF_BEGA + 256;
constexpr size_t OFF_FLAG  = OFF_BEGB + 256;                    // int dtype flag
constexpr size_t OFF_STAGE = OFF_FLAG + 256;                    // bf16 [T][NV][C]
constexpr size_t NEED_STAGE= OFF_STAGE + SZ_AGGT;               // ~157.6 MB

// ---- mega-kernel LDS layout (bytes). pitches chosen for <=2-way banks ----
constexpr int PITCH = 68;   // ushorts; row stride 136B -> bank stride 34 -> 2-way
constexpr int PEG   = 20;   // ushorts; 40B -> 10 dwords -> 2-way
constexpr int L_WIT = 0;                  // [192][68] bf16 = 26112
constexpr int L_WHT = 26112;              // 26112
constexpr int L_W1H = 52224;              // [64][68]  = 8704
constexpr int L_W2  = 60928;              // 8704
constexpr int L_WDEC= 69632;              // [16][68]  = 2176
constexpr int L_WEG = 71808;              // [64][20]  = 2560
constexpr int L_FB  = 74368;              // float[336] (pad 1408)
constexpr int L_H   = 75776;              // bf16[16][64] = 2048
constexpr int L_M   = 77824;              // 2048
constexpr int L_AGG = 79872;              // bf16[16][16] = 512
constexpr int L_S   = 80384;              // float[16]
constexpr int LDS_MEGA = 80448;           // <= 81920 -> 2 blocks/CU

#define DEVI __device__ __forceinline__

DEVI float bf2f(u16 u) {
    unsigned int v = ((unsigned int)u) << 16;
    float f; __builtin_memcpy(&f, &v, 4); return f;
}
DEVI u16 f2bf(float f) {   // round-to-nearest-even
    unsigned int v; __builtin_memcpy(&v, &f, 4);
    unsigned int r = (v + 0x7fffu + ((v >> 16) & 1u)) >> 16;
    return (u16)r;
}
// dtype-flag-aware scalar load: element i of a float32 OR bf16 buffer
DEVI float ldf(const void* p, size_t i, int f32) {
    return f32 ? ((const float*)p)[i] : bf2f(((const u16*)p)[i]);
}
DEVI float4 bf4(const u16* p) {
    ushort4 u = *reinterpret_cast<const ushort4*>(p);
    return make_float4(bf2f(u.x), bf2f(u.y), bf2f(u.z), bf2f(u.w));
}
DEVI float dot4(float4 a, float4 b) {
    return a.x*b.x + a.y*b.y + a.z*b.z + a.w*b.w;
}
DEVI float sigm(float v) { return 1.f / (1.f + __expf(-v)); }
DEVI float tanh_(float v) {   // overflow-safe tanh via exp of -2|x|
    float a = fabsf(v);
    float e = __expf(-2.f * a);
    float t = (1.f - e) / (1.f + e);
    return v < 0.f ? -t : t;
}

// transposed weight loads into LDS: dst[o*pitch + k] = src[k*O + o]
DEVI void loadT64(u16* dst, const void* src, int O, int pitch, int f32) {
    for (int i = threadIdx.x; i < 64 * O; i += 256) {
        int o = i >> 6, k = i & 63;
        dst[o * pitch + k] = f2bf(ldf(src, (size_t)k * O + o, f32));
    }
}
DEVI void loadT16(u16* dst, const void* src, int O, int pitch, int f32) {
    for (int i = threadIdx.x; i < 16 * O; i += 256) {
        int o = i >> 4, k = i & 15;
        dst[o * pitch + k] = f2bf(ldf(src, (size_t)k * O + o, f32));
    }
}
DEVI void loadBias(float* dst, const void* src, int n, int f32) {
    for (int i = threadIdx.x; i < n; i += 256) dst[i] = ldf(src, i, f32);
}

// out[16 x 64] += act[16 x 64] @ W[64 x 64]   (WT layout [o][k], per-thread 4 rows)
DEVI void gemm64(const u16* WT, const u16* act, int l, int rb,
                 const float init[4], float out[4]) {
    const u16* w  = WT + l * PITCH;
    const u16* a0 = act + (rb +  0) * 64;
    const u16* a1 = act + (rb +  4) * 64;
    const u16* a2 = act + (rb +  8) * 64;
    const u16* a3 = act + (rb + 12) * 64;
    float o0 = init[0], o1 = init[1], o2 = init[2], o3 = init[3];
#pragma unroll
    for (int k4 = 0; k4 < 16; ++k4) {
        float4 wv = bf4(w + 4 * k4);
        o0 += dot4(bf4(a0 + 4 * k4), wv);
        o1 += dot4(bf4(a1 + 4 * k4), wv);
        o2 += dot4(bf4(a2 + 4 * k4), wv);
        o3 += dot4(bf4(a3 + 4 * k4), wv);
    }
    out[0] = o0; out[1] = o1; out[2] = o2; out[3] = o3;
}

// fused GRU gate GEMMs: gi = m@Wi + b, gh = h@Wh ; z/r summed, n parts separate
DEVI void gruGemm(const u16* WiT, const u16* WhT, const u16* mS, const u16* hS,
                  int l, int rb, const float* bg,
                  float az[4], float ar[4], float ani[4], float anh[4]) {
#pragma unroll
    for (int j = 0; j < 4; ++j) {
        az[j] = bg[l]; ar[j] = bg[64 + l]; ani[j] = bg[128 + l]; anh[j] = 0.f;
    }
    const u16* wz = WiT + (  0 + l) * PITCH;
    const u16* wr = WiT + ( 64 + l) * PITCH;
    const u16* wn = WiT + (128 + l) * PITCH;
    const u16* vz = WhT + (  0 + l) * PITCH;
    const u16* vr = WhT + ( 64 + l) * PITCH;
    const u16* vn = WhT + (128 + l) * PITCH;
#pragma unroll
    for (int k4 = 0; k4 < 16; ++k4) {
        float4 a = bf4(wz + 4*k4), b = bf4(wr + 4*k4), c = bf4(wn + 4*k4);
        float4 d = bf4(vz + 4*k4), e = bf4(vr + 4*k4), f = bf4(vn + 4*k4);
#pragma unroll
        for (int j = 0; j < 4; ++j) {
            int r = rb + 4 * j;
            float4 mm = bf4(mS + r * 64 + 4 * k4);
            float4 hh = bf4(hS + r * 64 + 4 * k4);
            az[j]  += dot4(mm, a) + dot4(hh, d);
            ar[j]  += dot4(mm, b) + dot4(hh, e);
            ani[j] += dot4(mm, c);
            anh[j] += dot4(hh, f);
        }
    }
}

// m = agg_c @ W_eg + S * b_eg  -> mS (bf16)
DEVI void mcalc(const u16* WegT, const u16* aggS, const float* beg,
                const float* Sl, int l, int rb, u16* mS) {
    const u16* w = WegT + l * PEG;
    float4 w0 = bf4(w), w1 = bf4(w + 4), w2 = bf4(w + 8), w3 = bf4(w + 12);
#pragma unroll
    for (int j = 0; j < 4; ++j) {
        int r = rb + 4 * j;
        float acc = Sl[r] * beg[l];
        acc += dot4(bf4(aggS + r*16     ), w0) + dot4(bf4(aggS + r*16 +  4), w1)
             + dot4(bf4(aggS + r*16 +  8), w2) + dot4(bf4(aggS + r*16 + 12), w3);
        mS[r * 64 + l] = f2bf(acc);
    }
}

DEVI void decodeStore(const u16* WdT, const u16* hS, const float* bd,
                      int rg, int cg, void* outp, int staged, int isf32,
                      int base, int t) {
    float acc = bd[cg];
    const u16* w = WdT + cg * PITCH;
    const u16* a = hS + rg * 64;
#pragma unroll
    for (int k4 = 0; k4 < 16; ++k4) acc += dot4(bf4(w + 4*k4), bf4(a + 4*k4));
    if (staged) {
        ((u16*)outp)[((size_t)t * NV_ + base + rg) * C_ + cg] = f2bf(acc);
    } else {
        size_t off = (size_t)(base + rg) * CT_ + (size_t)cg * T_ + t;
        if (isf32) ((float*)outp)[off] = acc;
        else       ((u16*)outp)[off] = f2bf(acc);
    }
}

// ---------------------------------------------------------------------------
// dtype detection: interpret first 1024 u16 of x as bf16. True bf16 N(0,1)
// data has exponent field <= ~0x81. f32 data misread as bf16 gives ~40% of
// the low-half u16s an exponent >= 0x9A (|v| >= 2^27). Count >= 8 -> f32.
// ---------------------------------------------------------------------------
__global__ void k_detect(const u16* __restrict__ x, int* __restrict__ flag) {
    __shared__ int cnt;
    if (threadIdx.x == 0) cnt = 0;
    __syncthreads();
    int local = 0;
#pragma unroll
    for (int j = 0; j < 4; ++j) {
        u16 u = x[threadIdx.x * 4 + j];
        int ex = (u >> 7) & 0xFF;
        if (ex >= 0x9A) ++local;
    }
    if (local) atomicAdd(&cnt, local);
    __syncthreads();
    if (threadIdx.x == 0) *flag = (cnt >= 8) ? 1 : 0;
}

// ---------------------------------------------------------------------------
// CSR build
// ---------------------------------------------------------------------------
__global__ void k_count(const int* __restrict__ ei, const void* __restrict__ eattr,
                        const int* __restrict__ flag,
                        int* __restrict__ counts, float* __restrict__ S) {
    int f32 = *flag;
    int e = blockIdx.x * 256 + threadIdx.x;
    if (e < E_) {
        int dst = ei[E_ + e];
        atomicAdd(&counts[dst], 1);
        atomicAdd(&S[dst], ldf(eattr, e, f32));
    }
}

__global__ void k_scan(const int* __restrict__ counts, int* __restrict__ row_ptr,
                       int* __restrict__ cursor) {
    __shared__ int lds[256];
    int tid = threadIdx.x;
    int base = tid * 8, loc[8], s = 0;
#pragma unroll
    for (int i = 0; i < 8; ++i) { loc[i] = s; s += counts[base + i]; }
    lds[tid] = s; __syncthreads();
    for (int d = 1; d < 256; d <<= 1) {
        int v = (tid >= d) ? lds[tid - d] : 0;
        __syncthreads();
        lds[tid] += v;
        __syncthreads();
    }
    int off = (tid == 0) ? 0 : lds[tid - 1];
#pragma unroll
    for (int i = 0; i < 8; ++i) {
        int rp = off + loc[i];
        row_ptr[base + i] = rp; cursor[base + i] = rp;
    }
    if (tid == 255) row_ptr[V_] = lds[255];
}

__global__ void k_fill(const int* __restrict__ ei, const void* __restrict__ eattr,
                       const int* __restrict__ flag,
                       int* __restrict__ cursor, int* __restrict__ col_src,
                       float* __restrict__ col_att) {
    int f32 = *flag;
    int e = blockIdx.x * 256 + threadIdx.x;
    if (e < E_) {
        int dst = ei[E_ + e];
        int pos = atomicAdd(&cursor[dst], 1);
        col_src[pos] = ei[e];
        col_att[pos] = ldf(eattr, e, f32);
    }
}

// fused weights: W_egX = W_enc @ W_gX ; b_egX = b_enc @ W_gX
__global__ void k_wprep(const void* __restrict__ W_enc, const void* __restrict__ b_enc,
                        const void* __restrict__ W_gd, const void* __restrict__ W_gc,
                        const int* __restrict__ flag,
                        u16* __restrict__ wegA, u16* __restrict__ wegB,
                        float* __restrict__ begA, float* __restrict__ begB) {
    int f32 = *flag;
    int tid = threadIdx.x;
    for (int idx = tid; idx < 1024; idx += 256) {
        int c = idx >> 6, l = idx & 63;
        float sa = 0.f, sb = 0.f;
        for (int k = 0; k < 64; ++k) {
            float we = ldf(W_enc, c * 64 + k, f32);
            sa += we * ldf(W_gd, k * 64 + l, f32);
            sb += we * ldf(W_gc, k * 64 + l, f32);
        }
        wegA[idx] = f2bf(sa); wegB[idx] = f2bf(sb);
    }
    if (tid < 64) {
        float sa = 0.f, sb = 0.f;
        for (int k = 0; k < 64; ++k) {
            float be = ldf(b_enc, k, f32);
            sa += be * ldf(W_gd, k * 64 + tid, f32);
            sb += be * ldf(W_gc, k * 64 + tid, f32);
        }
        begA[tid] = sa; begB[tid] = sb;
    }
}

// ---------------------------------------------------------------------------
// pre-aggregation: aggT[t][n][v][c] = sum_{e: dst=v} attr_e * x[n, src_e, c, t]
// block = (n, 4 dst nodes); x rows are contiguous (c,t) slabs -> coalesced.
// ---------------------------------------------------------------------------
__global__ __launch_bounds__(256) void k_agg(
    const void* __restrict__ x, const int* __restrict__ flag,
    const int* __restrict__ row_ptr,
    const int* __restrict__ col_src, const float* __restrict__ col_att,
    u16* __restrict__ aggT) {
    __shared__ float lbuf[4 * CT_];   // 38,400 B
    int f32 = *flag;
    int tid = threadIdx.x;
    int n  = blockIdx.x >> 9;
    int v0 = (blockIdx.x & 511) * 4;
    for (int d = 0; d < 4; ++d) {
        int v = v0 + d;
        int e0 = row_ptr[v], e1 = row_ptr[v + 1];
        float acc[10];
#pragma unroll
        for (int k = 0; k < 10; ++k) acc[k] = 0.f;
        for (int e = e0; e < e1; ++e) {
            float a = col_att[e];
            size_t ro = (size_t)(n * V_ + col_src[e]) * CT_;
            if (f32) {
                const float* xr = (const float*)x + ro;
#pragma unroll
                for (int k = 0; k < 10; ++k) {
                    int idx = tid + 256 * k;
                    if (idx < CT_) acc[k] += a * xr[idx];
                }
            } else {
                const u16* xr = (const u16*)x + ro;
#pragma unroll
                for (int k = 0; k < 10; ++k) {
                    int idx = tid + 256 * k;
                    if (idx < CT_) acc[k] += a * bf2f(xr[idx]);
                }
            }
        }
#pragma unroll
        for (int k = 0; k < 10; ++k) {
            int idx = tid + 256 * k;
            if (idx < CT_) lbuf[d * CT_ + idx] = acc[k];
        }
    }
    __syncthreads();
    // write in [t][n][v][c] order (128B contiguous per t)
    for (int w = tid; w < 4 * CT_; w += 256) {
        int t = w >> 6, rem = w & 63, d = rem >> 4, c = rem & 15;
        aggT[((size_t)(t * N_ + n) * V_ + v0 + d) * C_ + c] =
            f2bf(lbuf[d * CT_ + c * T_ + t]);
    }
}

// ---------------------------------------------------------------------------
// mega kernel: phase A (domain GRU, 150 steps) -> dom MLP + zdterm ->
// phase B (ODE + GRU + decode, steps 1..149). 16 rows / block, all row-local.
// thread maps: (l = tid&63, rows rb+4j) for GEMMs; (rg = tid>>4, cg = tid&15)
// for agg/x0/decode.
// amdgpu_waves_per_eu(2,2): LDS (80.4KB) caps at 2 blocks/CU = 8 waves/CU =
// 2 waves/EU; pin the allocator to that so its VGPR budget is 256 and the
// unrolled GEMM live ranges never spill to scratch (rounds 0/1 were
// spill-traffic-bound at ~3.47 TB/s).
// ---------------------------------------------------------------------------
__global__
__attribute__((amdgpu_flat_work_group_size(256, 256)))
__attribute__((amdgpu_waves_per_eu(2, 2)))
void k_mega(
    const void* __restrict__ x, const u16* __restrict__ aggT,
    const float* __restrict__ Sg, const int* __restrict__ flag,
    const void* __restrict__ W_enc, const void* __restrict__ b_enc,
    const void* __restrict__ gd_Wi, const void* __restrict__ gd_Wh, const void* __restrict__ gd_b,
    const void* __restrict__ W_dom1, const void* __restrict__ b_dom1,
    const void* __restrict__ W_dom2, const void* __restrict__ b_dom2,
    const void* __restrict__ ode_W1, const void* __restrict__ ode_b1,
    const void* __restrict__ ode_W2, const void* __restrict__ ode_b2,
    const void* __restrict__ gc_Wi, const void* __restrict__ gc_Wh, const void* __restrict__ gc_b,
    const void* __restrict__ W_dec, const void* __restrict__ b_dec,
    const u16* __restrict__ wegA, const u16* __restrict__ wegB,
    const float* __restrict__ begA, const float* __restrict__ begB,
    void* __restrict__ outp, int staged) {
    extern __shared__ char smem[];
    u16* WiT  = (u16*)(smem + L_WIT);
    u16* WhT  = (u16*)(smem + L_WHT);
    u16* W1hT = (u16*)(smem + L_W1H);
    u16* W2T  = (u16*)(smem + L_W2);
    u16* WdT  = (u16*)(smem + L_WDEC);
    u16* WegT = (u16*)(smem + L_WEG);
    float* fB = (float*)(smem + L_FB);    // [0..191] gate bias, [192..255] b_eg,
                                          // [256..319] ode_b2, [320..335] b_dec
    u16* hS   = (u16*)(smem + L_H);
    u16* mS   = (u16*)(smem + L_M);
    u16* aggS = (u16*)(smem + L_AGG);
    float* Sl = (float*)(smem + L_S);

    const int f32 = *flag;
    const int tid = threadIdx.x;
    const int l = tid & 63, rb = tid >> 6;
    const int rg = tid >> 4, cg = tid & 15;
    const int base = blockIdx.x * 16;
    const int n = base >> 11, v0 = base & 2047;

    // ---- phase A setup
    loadT64(WiT, gd_Wi, 192, PITCH, f32);
    loadT64(WhT, gd_Wh, 192, PITCH, f32);
    for (int i = tid; i < 16 * 64; i += 256) {     // wegA already bf16
        int o = i >> 4, k = i & 15;
        WegT[o * PEG + k] = wegA[k * 64 + o];
    }
    loadBias(fB, gd_b, 192, f32);
    for (int i = tid; i < 64; i += 256) fB[192 + i] = begA[i];
    if (tid < 16) Sl[tid] = Sg[v0 + tid];
    __syncthreads();

    float hd[4] = {0.f, 0.f, 0.f, 0.f};
    // 1-step register prefetch of the 512B aggT slice
    u16 pf = aggT[((size_t)(0 * N_ + n) * V_ + v0) * C_ + tid];
    for (int t = 0; t < T_; ++t) {
        aggS[tid] = pf;
        if (t + 1 < T_)
            pf = aggT[((size_t)((t + 1) * N_ + n) * V_ + v0) * C_ + tid];
#pragma unroll
        for (int j = 0; j < 4; ++j) hS[(rb + 4*j) * 64 + l] = f2bf(hd[j]);
        __syncthreads();
        mcalc(WegT, aggS, fB + 192, Sl, l, rb, mS);
        __syncthreads();
        float az[4], ar[4], ani[4], anh[4];
        gruGemm(WiT, WhT, mS, hS, l, rb, fB, az, ar, ani, anh);
#pragma unroll
        for (int j = 0; j < 4; ++j) {
            float z = sigm(az[j]);
            float r = sigm(ar[j]);
            float nn = tanh_(ani[j] + r * anh[j]);
            hd[j] = (1.f - z) * nn + z * hd[j];
        }
        __syncthreads();
    }

    // ---- domain MLP: z_D = tanh(hd@Wdom1+b1)@Wdom2+b2 ; zdterm = zD@W1[64:]+ode_b1
#pragma unroll
    for (int j = 0; j < 4; ++j) hS[(rb + 4*j) * 64 + l] = f2bf(hd[j]);
    loadT64(W1hT, W_dom1, 64, PITCH, f32);
    loadT64(W2T,  W_dom2, 64, PITCH, f32);
    loadT64(WiT,  (const void*)((const char*)ode_W1 + (size_t)64 * 64 * (f32 ? 4 : 2)),
            64, PITCH, f32);   // zD half of ode_W1
    loadBias(fB,       b_dom1, 64, f32);
    loadBias(fB + 64,  b_dom2, 64, f32);
    loadBias(fB + 128, ode_b1, 64, f32);
    __syncthreads();
    float init4[4], tmp4[4];
#pragma unroll
    for (int j = 0; j < 4; ++j) init4[j] = fB[l];
    gemm64(W1hT, hS, l, rb, init4, tmp4);
#pragma unroll
    for (int j = 0; j < 4; ++j) mS[(rb + 4*j) * 64 + l] = f2bf(tanh_(tmp4[j]));
    __syncthreads();
    float zD[4];
#pragma unroll
    for (int j = 0; j < 4; ++j) init4[j] = fB[64 + l];
    gemm64(W2T, mS, l, rb, init4, zD);
    __syncthreads();
#pragma unroll
    for (int j = 0; j < 4; ++j) hS[(rb + 4*j) * 64 + l] = f2bf(zD[j]);
    __syncthreads();
    float zt[4];
#pragma unroll
    for (int j = 0; j < 4; ++j) init4[j] = fB[128 + l];
    gemm64(WiT, hS, l, rb, init4, zt);
    __syncthreads();

    // ---- phase B setup
    loadT64(WiT, gc_Wi, 192, PITCH, f32);
    loadT64(WhT, gc_Wh, 192, PITCH, f32);
    loadT64(W1hT, ode_W1, 64, PITCH, f32);   // h half
    loadT64(W2T,  ode_W2, 64, PITCH, f32);
    loadT64(WdT,  W_dec, 16, PITCH, f32);
    loadT16(WegT, W_enc, 64, PEG, f32);      // raw W_enc for h0
    loadBias(fB, b_enc, 64, f32);
    loadBias(fB + 256, ode_b2, 64, f32);
    loadBias(fB + 320, b_dec, 16, f32);
    for (int i = tid; i < 64; i += 256) fB[192 + i] = begB[i];
    __syncthreads();
    // h0 = x[:,:,:,0] @ W_enc + b_enc
    aggS[tid] = f2bf(ldf(x, (size_t)(base + rg) * CT_ + (size_t)cg * T_, f32));
    __syncthreads();
    float h[4];
    {
        const u16* w = WegT + l * PEG;
        float4 w0 = bf4(w), w1 = bf4(w+4), w2 = bf4(w+8), w3 = bf4(w+12);
#pragma unroll
        for (int j = 0; j < 4; ++j) {
            int r = rb + 4 * j;
            float acc = fB[l];
            acc += dot4(bf4(aggS + r*16), w0) + dot4(bf4(aggS + r*16 + 4), w1)
                 + dot4(bf4(aggS + r*16 + 8), w2) + dot4(bf4(aggS + r*16 + 12), w3);
            h[j] = acc;
            hS[r * 64 + l] = f2bf(acc);
        }
    }
    __syncthreads();
    decodeStore(WdT, hS, fB + 320, rg, cg, outp, staged, f32, base, 0);
    for (int i = tid; i < 16 * 64; i += 256) {     // wegB already bf16
        int o = i >> 4, k = i & 15;
        WegT[o * PEG + k] = wegB[k * 64 + o];
    }
    loadBias(fB, gc_b, 192, f32);
    __syncthreads();

    // prefetch t=1 agg slice
    pf = aggT[((size_t)(1 * N_ + n) * V_ + v0) * C_ + tid];
    for (int t = 1; t < T_; ++t) {
        // s1: agg stage (prefetched) + ODE hidden u = tanh(h@W1h + zdterm)
        aggS[tid] = pf;
        if (t + 1 < T_)
            pf = aggT[((size_t)((t + 1) * N_ + n) * V_ + v0) * C_ + tid];
        float u[4];
        gemm64(W1hT, hS, l, rb, zt, u);
#pragma unroll
        for (int j = 0; j < 4; ++j) mS[(rb + 4*j) * 64 + l] = f2bf(tanh_(u[j]));
        __syncthreads();
        // s2: dh = u@W2 + b2 ; h_ode = h + dh
        float dh[4];
#pragma unroll
        for (int j = 0; j < 4; ++j) init4[j] = fB[256 + l];
        gemm64(W2T, mS, l, rb, init4, dh);
        float ho[4];
#pragma unroll
        for (int j = 0; j < 4; ++j) ho[j] = h[j] + dh[j];
        __syncthreads();
        // s3: stage h_ode ; m = agg@W_eg + S*b_eg
#pragma unroll
        for (int j = 0; j < 4; ++j) hS[(rb + 4*j) * 64 + l] = f2bf(ho[j]);
        mcalc(WegT, aggS, fB + 192, Sl, l, rb, mS);
        __syncthreads();
        // s4: GRU(m, h_ode)
        float az[4], ar[4], ani[4], anh[4];
        gruGemm(WiT, WhT, mS, hS, l, rb, fB, az, ar, ani, anh);
#pragma unroll
        for (int j = 0; j < 4; ++j) {
            float z = sigm(az[j]);
            float r = sigm(ar[j]);
            float nn = tanh_(ani[j] + r * anh[j]);
            h[j] = (1.f - z) * nn + z * ho[j];
        }
        __syncthreads();
        // s5: stage h_new, decode
#pragma unroll
        for (int j = 0; j < 4; ++j) hS[(rb + 4*j) * 64 + l] = f2bf(h[j]);
        __syncthreads();
        decodeStore(WdT, hS, fB + 320, rg, cg, outp, staged, f32, base, t);
    }
}

// de-transpose staged output [t][row][c] -> d_out [row][c][t]
__global__ __launch_bounds__(256) void k_detrans(const u16* __restrict__ stage,
                                                 const int* __restrict__ flag,
                                                 void* __restrict__ out) {
    __shared__ u16 lt[8 * CT_];   // 38,400 B
    int f32 = *flag;
    int tid = threadIdx.x;
    int base = blockIdx.x * 8;
    int r = tid >> 4, c = tid & 15;
    for (int t = 0; t < T_; ++t) {
        if (tid < 128)
            lt[r * CT_ + c * T_ + t] = stage[((size_t)t * NV_ + base + r) * C_ + c];
    }
    __syncthreads();
    size_t ob = (size_t)base * CT_;
    if (f32) {
        float* o = (float*)out;
        for (int i = tid; i < 8 * CT_; i += 256) o[ob + i] = bf2f(lt[i]);
    } else {
        u16* o = (u16*)out;
        for (int i = tid; i < 8 * CT_; i += 256) o[ob + i] = lt[i];
    }
}

// ---------------------------------------------------------------------------
extern "C" void kernel_launch(void* const* d_in, const int* in_sizes, int n_in,
                              void* d_out, int out_size, void* d_ws, size_t ws_size,
                              hipStream_t stream) {
    const void* x      = d_in[0];
    const int*  ei     = (const int*)d_in[1];
    const void* eattr  = d_in[2];
    const void* W_enc  = d_in[3];
    const void* b_enc  = d_in[4];
    const void* W_gd   = d_in[5];
    const void* gd_Wi  = d_in[6];
    const void* gd_Wh  = d_in[7];
    const void* gd_b   = d_in[8];
    const void* W_dom1 = d_in[9];
    const void* b_dom1 = d_in[10];
    const void* W_dom2 = d_in[11];
    const void* b_dom2 = d_in[12];
    const void* ode_W1 = d_in[13];
    const void* ode_b1 = d_in[14];
    const void* ode_W2 = d_in[15];
    const void* ode_b2 = d_in[16];
    const void* W_gc   = d_in[17];
    const void* gc_Wi  = d_in[18];
    const void* gc_Wh  = d_in[19];
    const void* gc_b   = d_in[20];
    const void* W_dec  = d_in[21];
    const void* b_dec  = d_in[22];

    char* ws = (char*)d_ws;
    u16*   aggT    = (u16*)  (ws + OFF_AGGT);
    int*   counts  = (int*)  (ws + OFF_COUNTS);
    float* S       = (float*)(ws + OFF_S);
    int*   row_ptr = (int*)  (ws + OFF_RP);
    int*   cursor  = (int*)  (ws + OFF_CUR);
    int*   col_src = (int*)  (ws + OFF_CSRC);
    float* col_att = (float*)(ws + OFF_CATT);
    u16*   wegA    = (u16*)  (ws + OFF_WEGA);
    u16*   wegB    = (u16*)  (ws + OFF_WEGB);
    float* begA    = (float*)(ws + OFF_BEGA);
    float* begB    = (float*)(ws + OFF_BEGB);
    int*   flag    = (int*)  (ws + OFF_FLAG);
    u16*   stage   = (u16*)  (ws + OFF_STAGE);

    int staged = (ws_size >= NEED_STAGE) ? 1 : 0;
    void* mega_out = staged ? (void*)stage : d_out;

    // allow >64KB dynamic LDS (no-op where not required); idempotent per call
    (void)hipFuncSetAttribute((const void*)k_mega,
                              hipFuncAttributeMaxDynamicSharedMemorySize, LDS_MEGA);

    hipLaunchKernelGGL(k_detect, dim3(1), dim3(256), 0, stream, (const u16*)x, flag);
    hipMemsetAsync(ws + OFF_COUNTS, 0, 16384, stream);  // counts + S
    hipLaunchKernelGGL(k_count, dim3(E_ / 256), dim3(256), 0, stream,
                       ei, eattr, flag, counts, S);
    hipLaunchKernelGGL(k_scan, dim3(1), dim3(256), 0, stream,
                       counts, row_ptr, cursor);
    hipLaunchKernelGGL(k_fill, dim3(E_ / 256), dim3(256), 0, stream,
                       ei, eattr, flag, cursor, col_src, col_att);
    hipLaunchKernelGGL(k_wprep, dim3(1), dim3(256), 0, stream,
                       W_enc, b_enc, W_gd, W_gc, flag, wegA, wegB, begA, begB);
    hipLaunchKernelGGL(k_agg, dim3(N_ * V_ / 4), dim3(256), 0, stream,
                       x, flag, row_ptr, col_src, col_att, aggT);
    hipLaunchKernelGGL(k_mega, dim3(NV_ / 16), dim3(256), LDS_MEGA, stream,
                       x, aggT, S, flag, W_enc, b_enc, gd_Wi, gd_Wh, gd_b,
                       W_dom1, b_dom1, W_dom2, b_dom2,
                       ode_W1, ode_b1, ode_W2, ode_b2,
                       gc_Wi, gc_Wh, gc_b, W_dec, b_dec,
                       wegA, wegB, begA, begB, mega_out, staged);
    if (staged)
        hipLaunchKernelGGL(k_detrans, dim3(NV_ / 8), dim3(256), 0, stream,
                           stage, flag, d_out);
}

// Round 3
// 9910.078 us; speedup vs baseline: 8.0389x; 3.6815x over previous
//
#include <hip/hip_runtime.h>
#include <hip/hip_bf16.h>

// ---------------------------------------------------------------------------
// BayesianFilter: graph-GRU recurrent net.
// Key trick: gconv(xe_t) is linear in x_t, so edge aggregation is done ONCE in
// C-space (16 dims) for all t (k_agg), and the fused weight W_eg = W_enc@W_gX
// turns the per-step gconv into a row-local 16->64 matmul. After that the
// whole recurrence is row-parallel: one persistent kernel, no grid syncs.
//
// Round 5: spill elimination via unroll capping. Evidence from rounds 0-2:
// WRITE_SIZE 55-77 GB vs 78 MB of legitimate writes => scratch spill; traffic
// scales inversely with VGPR_Count (64->275GB, 128->97-131GB) at a constant
// ~3.5 TB/s => spill-traffic-bound. The VGPR budget is clamped at 128
// (512-reg SIMD pool / 4-waves-per-EU default) and amdgpu_waves_per_eu(2,2)
// did NOT lift it (round 2: VGPR stayed 128, perf regressed). Fix: make
// demand fit the budget. The fully-unrolled GEMM helpers let the scheduler
// hoist up to 96 ds_reads (~384 regs of temporaries) -> RA spills. Capping
// the k4 loops at unroll 2 (gruGemm/gemm64) and 4 (decodeStore) bounds
// in-flight temporaries to ~90 regs. Structure otherwise = verified round-0.
// ---------------------------------------------------------------------------

typedef unsigned short u16;

constexpr int N_ = 8, V_ = 2048, C_ = 16, T_ = 150, L_ = 64, E_ = 32768;
constexpr int NV_ = N_ * V_;             // 16384 rows
constexpr int CT_ = C_ * T_;             // 2400

// ---- workspace layout (bytes) ----
constexpr size_t SZ_AGGT   = (size_t)T_ * N_ * V_ * C_ * 2;     // 78,643,200 bf16
constexpr size_t OFF_AGGT  = 0;
constexpr size_t OFF_COUNTS= OFF_AGGT + SZ_AGGT;                // int[V]
constexpr size_t OFF_S     = OFF_COUNTS + 8192;                 // float[V]
constexpr size_t OFF_RP    = OFF_S + 8192;                      // int[V+1] (pad)
constexpr size_t OFF_CUR   = OFF_RP + 8448;                     // int[V]
constexpr size_t OFF_CSRC  = OFF_CUR + 8192;                    // int[E]
constexpr size_t OFF_CATT  = OFF_CSRC + 131072;                 // float[E]
constexpr size_t OFF_WEGA  = OFF_CATT + 131072;                 // bf16[16][64]
constexpr size_t OFF_WEGB  = OFF_WEGA + 2048;
constexpr size_t OFF_BEGA  = OFF_WEGB + 2048;                   // float[64]
constexpr size_t OFF_BEGB  = OFF_BEGA + 256;
constexpr size_t OFF_FLAG  = OFF_BEGB + 256;                    // int dtype flag
constexpr size_t OFF_STAGE = OFF_FLAG + 256;                    // bf16 [T][NV][C]
constexpr size_t NEED_STAGE= OFF_STAGE + SZ_AGGT;               // ~157.6 MB

// ---- mega-kernel LDS layout (bytes). pitches chosen for <=2-way banks ----
constexpr int PITCH = 68;   // ushorts; row stride 136B -> bank stride 34 -> 2-way
constexpr int PEG   = 20;   // ushorts; 40B -> 10 dwords -> 2-way
constexpr int L_WIT = 0;                  // [192][68] bf16 = 26112
constexpr int L_WHT = 26112;              // 26112
constexpr int L_W1H = 52224;              // [64][68]  = 8704
constexpr int L_W2  = 60928;              // 8704
constexpr int L_WDEC= 69632;              // [16][68]  = 2176
constexpr int L_WEG = 71808;              // [64][20]  = 2560
constexpr int L_FB  = 74368;              // float[336] (pad 1408)
constexpr int L_H   = 75776;              // bf16[16][64] = 2048
constexpr int L_M   = 77824;              // 2048
constexpr int L_AGG = 79872;              // bf16[16][16] = 512
constexpr int L_S   = 80384;              // float[16]
constexpr int LDS_MEGA = 80448;           // <= 81920 -> 2 blocks/CU

#define DEVI __device__ __forceinline__

DEVI float bf2f(u16 u) {
    unsigned int v = ((unsigned int)u) << 16;
    float f; __builtin_memcpy(&f, &v, 4); return f;
}
DEVI u16 f2bf(float f) {   // round-to-nearest-even
    unsigned int v; __builtin_memcpy(&v, &f, 4);
    unsigned int r = (v + 0x7fffu + ((v >> 16) & 1u)) >> 16;
    return (u16)r;
}
// dtype-flag-aware scalar load: element i of a float32 OR bf16 buffer
DEVI float ldf(const void* p, size_t i, int f32) {
    return f32 ? ((const float*)p)[i] : bf2f(((const u16*)p)[i]);
}
DEVI float4 bf4(const u16* p) {
    ushort4 u = *reinterpret_cast<const ushort4*>(p);
    return make_float4(bf2f(u.x), bf2f(u.y), bf2f(u.z), bf2f(u.w));
}
DEVI float dot4(float4 a, float4 b) {
    return a.x*b.x + a.y*b.y + a.z*b.z + a.w*b.w;
}
DEVI float sigm(float v) { return 1.f / (1.f + __expf(-v)); }
DEVI float tanh_(float v) {   // overflow-safe tanh via exp of -2|x|
    float a = fabsf(v);
    float e = __expf(-2.f * a);
    float t = (1.f - e) / (1.f + e);
    return v < 0.f ? -t : t;
}

// transposed weight loads into LDS: dst[o*pitch + k] = src[k*O + o]
DEVI void loadT64(u16* dst, const void* src, int O, int pitch, int f32) {
    for (int i = threadIdx.x; i < 64 * O; i += 256) {
        int o = i >> 6, k = i & 63;
        dst[o * pitch + k] = f2bf(ldf(src, (size_t)k * O + o, f32));
    }
}
DEVI void loadT16(u16* dst, const void* src, int O, int pitch, int f32) {
    for (int i = threadIdx.x; i < 16 * O; i += 256) {
        int o = i >> 4, k = i & 15;
        dst[o * pitch + k] = f2bf(ldf(src, (size_t)k * O + o, f32));
    }
}
DEVI void loadBias(float* dst, const void* src, int n, int f32) {
    for (int i = threadIdx.x; i < n; i += 256) dst[i] = ldf(src, i, f32);
}

// out[16 x 64] += act[16 x 64] @ W[64 x 64]   (WT layout [o][k], per-thread 4 rows)
// unroll 2: bound in-flight LDS-load temporaries, keep VGPR demand < 128
// (full unroll hoists up to 16x(1w+4act) float4s -> spill; see header note)
DEVI void gemm64(const u16* WT, const u16* act, int l, int rb,
                 const float init[4], float out[4]) {
    const u16* w  = WT + l * PITCH;
    const u16* a0 = act + (rb +  0) * 64;
    const u16* a1 = act + (rb +  4) * 64;
    const u16* a2 = act + (rb +  8) * 64;
    const u16* a3 = act + (rb + 12) * 64;
    float o0 = init[0], o1 = init[1], o2 = init[2], o3 = init[3];
#pragma unroll 2
    for (int k4 = 0; k4 < 16; ++k4) {
        float4 wv = bf4(w + 4 * k4);
        o0 += dot4(bf4(a0 + 4 * k4), wv);
        o1 += dot4(bf4(a1 + 4 * k4), wv);
        o2 += dot4(bf4(a2 + 4 * k4), wv);
        o3 += dot4(bf4(a3 + 4 * k4), wv);
    }
    out[0] = o0; out[1] = o1; out[2] = o2; out[3] = o3;
}

// fused GRU gate GEMMs: gi = m@Wi + b, gh = h@Wh ; z/r summed, n parts separate
// unroll 2: peak live ~= 16 acc + 2x(6w + 2act) float4 + addrs ~= 90 VGPRs
DEVI void gruGemm(const u16* WiT, const u16* WhT, const u16* mS, const u16* hS,
                  int l, int rb, const float* bg,
                  float az[4], float ar[4], float ani[4], float anh[4]) {
#pragma unroll
    for (int j = 0; j < 4; ++j) {
        az[j] = bg[l]; ar[j] = bg[64 + l]; ani[j] = bg[128 + l]; anh[j] = 0.f;
    }
    const u16* wz = WiT + (  0 + l) * PITCH;
    const u16* wr = WiT + ( 64 + l) * PITCH;
    const u16* wn = WiT + (128 + l) * PITCH;
    const u16* vz = WhT + (  0 + l) * PITCH;
    const u16* vr = WhT + ( 64 + l) * PITCH;
    const u16* vn = WhT + (128 + l) * PITCH;
#pragma unroll 2
    for (int k4 = 0; k4 < 16; ++k4) {
        float4 a = bf4(wz + 4*k4), b = bf4(wr + 4*k4), c = bf4(wn + 4*k4);
        float4 d = bf4(vz + 4*k4), e = bf4(vr + 4*k4), f = bf4(vn + 4*k4);
#pragma unroll
        for (int j = 0; j < 4; ++j) {
            int r = rb + 4 * j;
            float4 mm = bf4(mS + r * 64 + 4 * k4);
            float4 hh = bf4(hS + r * 64 + 4 * k4);
            az[j]  += dot4(mm, a) + dot4(hh, d);
            ar[j]  += dot4(mm, b) + dot4(hh, e);
            ani[j] += dot4(mm, c);
            anh[j] += dot4(hh, f);
        }
    }
}

// m = agg_c @ W_eg + S * b_eg  -> mS (bf16)
DEVI void mcalc(const u16* WegT, const u16* aggS, const float* beg,
                const float* Sl, int l, int rb, u16* mS) {
    const u16* w = WegT + l * PEG;
    float4 w0 = bf4(w), w1 = bf4(w + 4), w2 = bf4(w + 8), w3 = bf4(w + 12);
#pragma unroll
    for (int j = 0; j < 4; ++j) {
        int r = rb + 4 * j;
        float acc = Sl[r] * beg[l];
        acc += dot4(bf4(aggS + r*16     ), w0) + dot4(bf4(aggS + r*16 +  4), w1)
             + dot4(bf4(aggS + r*16 +  8), w2) + dot4(bf4(aggS + r*16 + 12), w3);
        mS[r * 64 + l] = f2bf(acc);
    }
}

// unroll 4: 2 float4 per iter -> <=32 hoisted temporaries
DEVI void decodeStore(const u16* WdT, const u16* hS, const float* bd,
                      int rg, int cg, void* outp, int staged, int isf32,
                      int base, int t) {
    float acc = bd[cg];
    const u16* w = WdT + cg * PITCH;
    const u16* a = hS + rg * 64;
#pragma unroll 4
    for (int k4 = 0; k4 < 16; ++k4) acc += dot4(bf4(w + 4*k4), bf4(a + 4*k4));
    if (staged) {
        ((u16*)outp)[((size_t)t * NV_ + base + rg) * C_ + cg] = f2bf(acc);
    } else {
        size_t off = (size_t)(base + rg) * CT_ + (size_t)cg * T_ + t;
        if (isf32) ((float*)outp)[off] = acc;
        else       ((u16*)outp)[off] = f2bf(acc);
    }
}

// ---------------------------------------------------------------------------
// dtype detection: interpret first 1024 u16 of x as bf16. True bf16 N(0,1)
// data has exponent field <= ~0x81. f32 data misread as bf16 gives ~40% of
// the low-half u16s an exponent >= 0x9A (|v| >= 2^27). Count >= 8 -> f32.
// ---------------------------------------------------------------------------
__global__ void k_detect(const u16* __restrict__ x, int* __restrict__ flag) {
    __shared__ int cnt;
    if (threadIdx.x == 0) cnt = 0;
    __syncthreads();
    int local = 0;
#pragma unroll
    for (int j = 0; j < 4; ++j) {
        u16 u = x[threadIdx.x * 4 + j];
        int ex = (u >> 7) & 0xFF;
        if (ex >= 0x9A) ++local;
    }
    if (local) atomicAdd(&cnt, local);
    __syncthreads();
    if (threadIdx.x == 0) *flag = (cnt >= 8) ? 1 : 0;
}

// ---------------------------------------------------------------------------
// CSR build
// ---------------------------------------------------------------------------
__global__ void k_count(const int* __restrict__ ei, const void* __restrict__ eattr,
                        const int* __restrict__ flag,
                        int* __restrict__ counts, float* __restrict__ S) {
    int f32 = *flag;
    int e = blockIdx.x * 256 + threadIdx.x;
    if (e < E_) {
        int dst = ei[E_ + e];
        atomicAdd(&counts[dst], 1);
        atomicAdd(&S[dst], ldf(eattr, e, f32));
    }
}

__global__ void k_scan(const int* __restrict__ counts, int* __restrict__ row_ptr,
                       int* __restrict__ cursor) {
    __shared__ int lds[256];
    int tid = threadIdx.x;
    int base = tid * 8, loc[8], s = 0;
#pragma unroll
    for (int i = 0; i < 8; ++i) { loc[i] = s; s += counts[base + i]; }
    lds[tid] = s; __syncthreads();
    for (int d = 1; d < 256; d <<= 1) {
        int v = (tid >= d) ? lds[tid - d] : 0;
        __syncthreads();
        lds[tid] += v;
        __syncthreads();
    }
    int off = (tid == 0) ? 0 : lds[tid - 1];
#pragma unroll
    for (int i = 0; i < 8; ++i) {
        int rp = off + loc[i];
        row_ptr[base + i] = rp; cursor[base + i] = rp;
    }
    if (tid == 255) row_ptr[V_] = lds[255];
}

__global__ void k_fill(const int* __restrict__ ei, const void* __restrict__ eattr,
                       const int* __restrict__ flag,
                       int* __restrict__ cursor, int* __restrict__ col_src,
                       float* __restrict__ col_att) {
    int f32 = *flag;
    int e = blockIdx.x * 256 + threadIdx.x;
    if (e < E_) {
        int dst = ei[E_ + e];
        int pos = atomicAdd(&cursor[dst], 1);
        col_src[pos] = ei[e];
        col_att[pos] = ldf(eattr, e, f32);
    }
}

// fused weights: W_egX = W_enc @ W_gX ; b_egX = b_enc @ W_gX
__global__ void k_wprep(const void* __restrict__ W_enc, const void* __restrict__ b_enc,
                        const void* __restrict__ W_gd, const void* __restrict__ W_gc,
                        const int* __restrict__ flag,
                        u16* __restrict__ wegA, u16* __restrict__ wegB,
                        float* __restrict__ begA, float* __restrict__ begB) {
    int f32 = *flag;
    int tid = threadIdx.x;
    for (int idx = tid; idx < 1024; idx += 256) {
        int c = idx >> 6, l = idx & 63;
        float sa = 0.f, sb = 0.f;
        for (int k = 0; k < 64; ++k) {
            float we = ldf(W_enc, c * 64 + k, f32);
            sa += we * ldf(W_gd, k * 64 + l, f32);
            sb += we * ldf(W_gc, k * 64 + l, f32);
        }
        wegA[idx] = f2bf(sa); wegB[idx] = f2bf(sb);
    }
    if (tid < 64) {
        float sa = 0.f, sb = 0.f;
        for (int k = 0; k < 64; ++k) {
            float be = ldf(b_enc, k, f32);
            sa += be * ldf(W_gd, k * 64 + tid, f32);
            sb += be * ldf(W_gc, k * 64 + tid, f32);
        }
        begA[tid] = sa; begB[tid] = sb;
    }
}

// ---------------------------------------------------------------------------
// pre-aggregation: aggT[t][n][v][c] = sum_{e: dst=v} attr_e * x[n, src_e, c, t]
// block = (n, 4 dst nodes); x rows are contiguous (c,t) slabs -> coalesced.
// ---------------------------------------------------------------------------
__global__ __launch_bounds__(256) void k_agg(
    const void* __restrict__ x, const int* __restrict__ flag,
    const int* __restrict__ row_ptr,
    const int* __restrict__ col_src, const float* __restrict__ col_att,
    u16* __restrict__ aggT) {
    __shared__ float lbuf[4 * CT_];   // 38,400 B
    int f32 = *flag;
    int tid = threadIdx.x;
    int n  = blockIdx.x >> 9;
    int v0 = (blockIdx.x & 511) * 4;
    for (int d = 0; d < 4; ++d) {
        int v = v0 + d;
        int e0 = row_ptr[v], e1 = row_ptr[v + 1];
        float acc[10];
#pragma unroll
        for (int k = 0; k < 10; ++k) acc[k] = 0.f;
        for (int e = e0; e < e1; ++e) {
            float a = col_att[e];
            size_t ro = (size_t)(n * V_ + col_src[e]) * CT_;
            if (f32) {
                const float* xr = (const float*)x + ro;
#pragma unroll
                for (int k = 0; k < 10; ++k) {
                    int idx = tid + 256 * k;
                    if (idx < CT_) acc[k] += a * xr[idx];
                }
            } else {
                const u16* xr = (const u16*)x + ro;
#pragma unroll
                for (int k = 0; k < 10; ++k) {
                    int idx = tid + 256 * k;
                    if (idx < CT_) acc[k] += a * bf2f(xr[idx]);
                }
            }
        }
#pragma unroll
        for (int k = 0; k < 10; ++k) {
            int idx = tid + 256 * k;
            if (idx < CT_) lbuf[d * CT_ + idx] = acc[k];
        }
    }
    __syncthreads();
    // write in [t][n][v][c] order (128B contiguous per t)
    for (int w = tid; w < 4 * CT_; w += 256) {
        int t = w >> 6, rem = w & 63, d = rem >> 4, c = rem & 15;
        aggT[((size_t)(t * N_ + n) * V_ + v0 + d) * C_ + c] =
            f2bf(lbuf[d * CT_ + c * T_ + t]);
    }
}

// ---------------------------------------------------------------------------
// mega kernel: phase A (domain GRU, 150 steps) -> dom MLP + zdterm ->
// phase B (ODE + GRU + decode, steps 1..149). 16 rows / block, all row-local.
// thread maps: (l = tid&63, rows rb+4j) for GEMMs; (rg = tid>>4, cg = tid&15)
// for agg/x0/decode.
// ---------------------------------------------------------------------------
__global__ __launch_bounds__(256, 2) void k_mega(
    const void* __restrict__ x, const u16* __restrict__ aggT,
    const float* __restrict__ Sg, const int* __restrict__ flag,
    const void* __restrict__ W_enc, const void* __restrict__ b_enc,
    const void* __restrict__ gd_Wi, const void* __restrict__ gd_Wh, const void* __restrict__ gd_b,
    const void* __restrict__ W_dom1, const void* __restrict__ b_dom1,
    const void* __restrict__ W_dom2, const void* __restrict__ b_dom2,
    const void* __restrict__ ode_W1, const void* __restrict__ ode_b1,
    const void* __restrict__ ode_W2, const void* __restrict__ ode_b2,
    const void* __restrict__ gc_Wi, const void* __restrict__ gc_Wh, const void* __restrict__ gc_b,
    const void* __restrict__ W_dec, const void* __restrict__ b_dec,
    const u16* __restrict__ wegA, const u16* __restrict__ wegB,
    const float* __restrict__ begA, const float* __restrict__ begB,
    void* __restrict__ outp, int staged) {
    extern __shared__ char smem[];
    u16* WiT  = (u16*)(smem + L_WIT);
    u16* WhT  = (u16*)(smem + L_WHT);
    u16* W1hT = (u16*)(smem + L_W1H);
    u16* W2T  = (u16*)(smem + L_W2);
    u16* WdT  = (u16*)(smem + L_WDEC);
    u16* WegT = (u16*)(smem + L_WEG);
    float* fB = (float*)(smem + L_FB);    // [0..191] gate bias, [192..255] b_eg,
                                          // [256..319] ode_b2, [320..335] b_dec
    u16* hS   = (u16*)(smem + L_H);
    u16* mS   = (u16*)(smem + L_M);
    u16* aggS = (u16*)(smem + L_AGG);
    float* Sl = (float*)(smem + L_S);

    const int f32 = *flag;
    const int tid = threadIdx.x;
    const int l = tid & 63, rb = tid >> 6;
    const int rg = tid >> 4, cg = tid & 15;
    const int base = blockIdx.x * 16;
    const int n = base >> 11, v0 = base & 2047;

    // ---- phase A setup
    loadT64(WiT, gd_Wi, 192, PITCH, f32);
    loadT64(WhT, gd_Wh, 192, PITCH, f32);
    for (int i = tid; i < 16 * 64; i += 256) {     // wegA already bf16
        int o = i >> 4, k = i & 15;
        WegT[o * PEG + k] = wegA[k * 64 + o];
    }
    loadBias(fB, gd_b, 192, f32);
    for (int i = tid; i < 64; i += 256) fB[192 + i] = begA[i];
    if (tid < 16) Sl[tid] = Sg[v0 + tid];
    __syncthreads();

    float hd[4] = {0.f, 0.f, 0.f, 0.f};
    for (int t = 0; t < T_; ++t) {
        aggS[tid] = aggT[((size_t)(t * N_ + n) * V_ + v0) * C_ + tid];
#pragma unroll
        for (int j = 0; j < 4; ++j) hS[(rb + 4*j) * 64 + l] = f2bf(hd[j]);
        __syncthreads();
        mcalc(WegT, aggS, fB + 192, Sl, l, rb, mS);
        __syncthreads();
        float az[4], ar[4], ani[4], anh[4];
        gruGemm(WiT, WhT, mS, hS, l, rb, fB, az, ar, ani, anh);
#pragma unroll
        for (int j = 0; j < 4; ++j) {
            float z = sigm(az[j]);
            float r = sigm(ar[j]);
            float nn = tanh_(ani[j] + r * anh[j]);
            hd[j] = (1.f - z) * nn + z * hd[j];
        }
        __syncthreads();
    }

    // ---- domain MLP: z_D = tanh(hd@Wdom1+b1)@Wdom2+b2 ; zdterm = zD@W1[64:]+ode_b1
#pragma unroll
    for (int j = 0; j < 4; ++j) hS[(rb + 4*j) * 64 + l] = f2bf(hd[j]);
    loadT64(W1hT, W_dom1, 64, PITCH, f32);
    loadT64(W2T,  W_dom2, 64, PITCH, f32);
    loadT64(WiT,  (const void*)((const char*)ode_W1 + (size_t)64 * 64 * (f32 ? 4 : 2)),
            64, PITCH, f32);   // zD half of ode_W1
    loadBias(fB,       b_dom1, 64, f32);
    loadBias(fB + 64,  b_dom2, 64, f32);
    loadBias(fB + 128, ode_b1, 64, f32);
    __syncthreads();
    float init4[4], tmp4[4];
#pragma unroll
    for (int j = 0; j < 4; ++j) init4[j] = fB[l];
    gemm64(W1hT, hS, l, rb, init4, tmp4);
#pragma unroll
    for (int j = 0; j < 4; ++j) mS[(rb + 4*j) * 64 + l] = f2bf(tanh_(tmp4[j]));
    __syncthreads();
    float zD[4];
#pragma unroll
    for (int j = 0; j < 4; ++j) init4[j] = fB[64 + l];
    gemm64(W2T, mS, l, rb, init4, zD);
    __syncthreads();
#pragma unroll
    for (int j = 0; j < 4; ++j) hS[(rb + 4*j) * 64 + l] = f2bf(zD[j]);
    __syncthreads();
    float zt[4];
#pragma unroll
    for (int j = 0; j < 4; ++j) init4[j] = fB[128 + l];
    gemm64(WiT, hS, l, rb, init4, zt);
    __syncthreads();

    // ---- phase B setup
    loadT64(WiT, gc_Wi, 192, PITCH, f32);
    loadT64(WhT, gc_Wh, 192, PITCH, f32);
    loadT64(W1hT, ode_W1, 64, PITCH, f32);   // h half
    loadT64(W2T,  ode_W2, 64, PITCH, f32);
    loadT64(WdT,  W_dec, 16, PITCH, f32);
    loadT16(WegT, W_enc, 64, PEG, f32);      // raw W_enc for h0
    loadBias(fB, b_enc, 64, f32);
    loadBias(fB + 256, ode_b2, 64, f32);
    loadBias(fB + 320, b_dec, 16, f32);
    for (int i = tid; i < 64; i += 256) fB[192 + i] = begB[i];
    __syncthreads();
    // h0 = x[:,:,:,0] @ W_enc + b_enc
    aggS[tid] = f2bf(ldf(x, (size_t)(base + rg) * CT_ + (size_t)cg * T_, f32));
    __syncthreads();
    float h[4];
    {
        const u16* w = WegT + l * PEG;
        float4 w0 = bf4(w), w1 = bf4(w+4), w2 = bf4(w+8), w3 = bf4(w+12);
#pragma unroll
        for (int j = 0; j < 4; ++j) {
            int r = rb + 4 * j;
            float acc = fB[l];
            acc += dot4(bf4(aggS + r*16), w0) + dot4(bf4(aggS + r*16 + 4), w1)
                 + dot4(bf4(aggS + r*16 + 8), w2) + dot4(bf4(aggS + r*16 + 12), w3);
            h[j] = acc;
            hS[r * 64 + l] = f2bf(acc);
        }
    }
    __syncthreads();
    decodeStore(WdT, hS, fB + 320, rg, cg, outp, staged, f32, base, 0);
    for (int i = tid; i < 16 * 64; i += 256) {     // wegB already bf16
        int o = i >> 4, k = i & 15;
        WegT[o * PEG + k] = wegB[k * 64 + o];
    }
    loadBias(fB, gc_b, 192, f32);
    __syncthreads();

    for (int t = 1; t < T_; ++t) {
        // s1: agg load + ODE hidden u = tanh(h@W1h + zdterm)
        aggS[tid] = aggT[((size_t)(t * N_ + n) * V_ + v0) * C_ + tid];
        float u[4];
        gemm64(W1hT, hS, l, rb, zt, u);
#pragma unroll
        for (int j = 0; j < 4; ++j) mS[(rb + 4*j) * 64 + l] = f2bf(tanh_(u[j]));
        __syncthreads();
        // s2: dh = u@W2 + b2 ; h_ode = h + dh
        float dh[4];
#pragma unroll
        for (int j = 0; j < 4; ++j) init4[j] = fB[256 + l];
        gemm64(W2T, mS, l, rb, init4, dh);
        float ho[4];
#pragma unroll
        for (int j = 0; j < 4; ++j) ho[j] = h[j] + dh[j];
        __syncthreads();
        // s3: stage h_ode ; m = agg@W_eg + S*b_eg
#pragma unroll
        for (int j = 0; j < 4; ++j) hS[(rb + 4*j) * 64 + l] = f2bf(ho[j]);
        mcalc(WegT, aggS, fB + 192, Sl, l, rb, mS);
        __syncthreads();
        // s4: GRU(m, h_ode)
        float az[4], ar[4], ani[4], anh[4];
        gruGemm(WiT, WhT, mS, hS, l, rb, fB, az, ar, ani, anh);
#pragma unroll
        for (int j = 0; j < 4; ++j) {
            float z = sigm(az[j]);
            float r = sigm(ar[j]);
            float nn = tanh_(ani[j] + r * anh[j]);
            h[j] = (1.f - z) * nn + z * ho[j];
        }
        __syncthreads();
        // s5: stage h_new, decode
#pragma unroll
        for (int j = 0; j < 4; ++j) hS[(rb + 4*j) * 64 + l] = f2bf(h[j]);
        __syncthreads();
        decodeStore(WdT, hS, fB + 320, rg, cg, outp, staged, f32, base, t);
    }
}

// de-transpose staged output [t][row][c] -> d_out [row][c][t]
__global__ __launch_bounds__(256) void k_detrans(const u16* __restrict__ stage,
                                                 const int* __restrict__ flag,
                                                 void* __restrict__ out) {
    __shared__ u16 lt[8 * CT_];   // 38,400 B
    int f32 = *flag;
    int tid = threadIdx.x;
    int base = blockIdx.x * 8;
    int r = tid >> 4, c = tid & 15;
    for (int t = 0; t < T_; ++t) {
        if (tid < 128)
            lt[r * CT_ + c * T_ + t] = stage[((size_t)t * NV_ + base + r) * C_ + c];
    }
    __syncthreads();
    size_t ob = (size_t)base * CT_;
    if (f32) {
        float* o = (float*)out;
        for (int i = tid; i < 8 * CT_; i += 256) o[ob + i] = bf2f(lt[i]);
    } else {
        u16* o = (u16*)out;
        for (int i = tid; i < 8 * CT_; i += 256) o[ob + i] = lt[i];
    }
}

// ---------------------------------------------------------------------------
extern "C" void kernel_launch(void* const* d_in, const int* in_sizes, int n_in,
                              void* d_out, int out_size, void* d_ws, size_t ws_size,
                              hipStream_t stream) {
    const void* x      = d_in[0];
    const int*  ei     = (const int*)d_in[1];
    const void* eattr  = d_in[2];
    const void* W_enc  = d_in[3];
    const void* b_enc  = d_in[4];
    const void* W_gd   = d_in[5];
    const void* gd_Wi  = d_in[6];
    const void* gd_Wh  = d_in[7];
    const void* gd_b   = d_in[8];
    const void* W_dom1 = d_in[9];
    const void* b_dom1 = d_in[10];
    const void* W_dom2 = d_in[11];
    const void* b_dom2 = d_in[12];
    const void* ode_W1 = d_in[13];
    const void* ode_b1 = d_in[14];
    const void* ode_W2 = d_in[15];
    const void* ode_b2 = d_in[16];
    const void* W_gc   = d_in[17];
    const void* gc_Wi  = d_in[18];
    const void* gc_Wh  = d_in[19];
    const void* gc_b   = d_in[20];
    const void* W_dec  = d_in[21];
    const void* b_dec  = d_in[22];

    char* ws = (char*)d_ws;
    u16*   aggT    = (u16*)  (ws + OFF_AGGT);
    int*   counts  = (int*)  (ws + OFF_COUNTS);
    float* S       = (float*)(ws + OFF_S);
    int*   row_ptr = (int*)  (ws + OFF_RP);
    int*   cursor  = (int*)  (ws + OFF_CUR);
    int*   col_src = (int*)  (ws + OFF_CSRC);
    float* col_att = (float*)(ws + OFF_CATT);
    u16*   wegA    = (u16*)  (ws + OFF_WEGA);
    u16*   wegB    = (u16*)  (ws + OFF_WEGB);
    float* begA    = (float*)(ws + OFF_BEGA);
    float* begB    = (float*)(ws + OFF_BEGB);
    int*   flag    = (int*)  (ws + OFF_FLAG);
    u16*   stage   = (u16*)  (ws + OFF_STAGE);

    int staged = (ws_size >= NEED_STAGE) ? 1 : 0;
    void* mega_out = staged ? (void*)stage : d_out;

    // allow >64KB dynamic LDS (no-op where not required); idempotent per call
    (void)hipFuncSetAttribute((const void*)k_mega,
                              hipFuncAttributeMaxDynamicSharedMemorySize, LDS_MEGA);

    hipLaunchKernelGGL(k_detect, dim3(1), dim3(256), 0, stream, (const u16*)x, flag);
    hipMemsetAsync(ws + OFF_COUNTS, 0, 16384, stream);  // counts + S
    hipLaunchKernelGGL(k_count, dim3(E_ / 256), dim3(256), 0, stream,
                       ei, eattr, flag, counts, S);
    hipLaunchKernelGGL(k_scan, dim3(1), dim3(256), 0, stream,
                       counts, row_ptr, cursor);
    hipLaunchKernelGGL(k_fill, dim3(E_ / 256), dim3(256), 0, stream,
                       ei, eattr, flag, cursor, col_src, col_att);
    hipLaunchKernelGGL(k_wprep, dim3(1), dim3(256), 0, stream,
                       W_enc, b_enc, W_gd, W_gc, flag, wegA, wegB, begA, begB);
    hipLaunchKernelGGL(k_agg, dim3(N_ * V_ / 4), dim3(256), 0, stream,
                       x, flag, row_ptr, col_src, col_att, aggT);
    hipLaunchKernelGGL(k_mega, dim3(NV_ / 16), dim3(256), LDS_MEGA, stream,
                       x, aggT, S, flag, W_enc, b_enc, gd_Wi, gd_Wh, gd_b,
                       W_dom1, b_dom1, W_dom2, b_dom2,
                       ode_W1, ode_b1, ode_W2, ode_b2,
                       gc_Wi, gc_Wh, gc_b, W_dec, b_dec,
                       wegA, wegB, begA, begB, mega_out, staged);
    if (staged)
        hipLaunchKernelGGL(k_detrans, dim3(NV_ / 8), dim3(256), 0, stream,
                           stage, flag, d_out);
}

// Round 4
// 1998.618 us; speedup vs baseline: 39.8606x; 4.9585x over previous
//
#include <hip/hip_runtime.h>
#include <hip/hip_bf16.h>

// ---------------------------------------------------------------------------
// BayesianFilter: graph-GRU recurrent net.
// Round 6: MFMA rewrite of the recurrence. Round 3 eliminated scratch spill
// (hbm 97GB -> 0.18GB) leaving k_mega VALU-issue-bound (VALUBusy 87.5%,
// MfmaUtil 0). All per-step GEMMs are matmul-shaped (M=16,K=64,N<=192) ->
// moved to v_mfma_f32_16x16x32_bf16. Layouts (guide-verified, learn_hip m89):
//   A-frag: row=lane&15, k=(lane>>4)*8+j  (8 contig bf16 = ds_read_b128)
//   B-frag: col=lane&15, k=(lane>>4)*8+j  (weights stored transposed [O][64])
//   C/D   : col=lane&15, row=(lane>>4)*4+reg
// Each of 4 waves owns a 16-col slice of every GEMM output -> GRU pointwise
// update runs on C-layout registers, no cross-lane traffic. Weights in LDS
// pitch 64 (16B-aligned rows); activations pitch 72 (144B rows -> bank-
// rotated, balanced b128 frag reads); agg buffer pitch 40, K-padded to 32
// with zeros. Wi-gate + W_eg B-frags hoisted to registers (28 VGPR). The
// one-time domain MLP stays in the round-3-verified VALU form; zt crosses
// to C-layout via a f32 LDS scratch (reusing the WegT region). Register
// peak ~110 < the 128 clamp -> no spill (watch FETCH/WRITE to confirm).
// ---------------------------------------------------------------------------

typedef unsigned short u16;
typedef __bf16 bfx8 __attribute__((ext_vector_type(8)));
typedef float  fx4  __attribute__((ext_vector_type(4)));

constexpr int N_ = 8, V_ = 2048, C_ = 16, T_ = 150, L_ = 64, E_ = 32768;
constexpr int NV_ = N_ * V_;             // 16384 rows
constexpr int CT_ = C_ * T_;             // 2400
constexpr size_t AGST = (size_t)N_ * V_ * C_;   // aggT per-t stride

// ---- workspace layout (bytes) ----
constexpr size_t SZ_AGGT   = (size_t)T_ * N_ * V_ * C_ * 2;     // 78,643,200 bf16
constexpr size_t OFF_AGGT  = 0;
constexpr size_t OFF_COUNTS= OFF_AGGT + SZ_AGGT;                // int[V]
constexpr size_t OFF_S     = OFF_COUNTS + 8192;                 // float[V]
constexpr size_t OFF_RP    = OFF_S + 8192;                      // int[V+1] (pad)
constexpr size_t OFF_CUR   = OFF_RP + 8448;                     // int[V]
constexpr size_t OFF_CSRC  = OFF_CUR + 8192;                    // int[E]
constexpr size_t OFF_CATT  = OFF_CSRC + 131072;                 // float[E]
constexpr size_t OFF_WEGA  = OFF_CATT + 131072;                 // bf16[16][64]
constexpr size_t OFF_WEGB  = OFF_WEGA + 2048;
constexpr size_t OFF_BEGA  = OFF_WEGB + 2048;                   // float[64]
constexpr size_t OFF_BEGB  = OFF_BEGA + 256;
constexpr size_t OFF_FLAG  = OFF_BEGB + 256;                    // int dtype flag
constexpr size_t OFF_STAGE = OFF_FLAG + 256;                    // bf16 [T][NV][C]
constexpr size_t NEED_STAGE= OFF_STAGE + SZ_AGGT;               // ~157.6 MB

// ---- mega-kernel LDS layout (bytes), all bases 16B-aligned ----
constexpr int PH = 72;   // activation pitch (ushorts): 144B rows = 9x16B -> bank-rotated
constexpr int PA = 40;   // agg pitch: 80B rows = 5x16B
constexpr int L_WIT = 0;       // [192][64] bf16 = 24576 (Wi transposed)
constexpr int L_WHT = 24576;   // [192][64] = 24576 (Wh transposed)
constexpr int L_W1H = 49152;   // [64][64]  = 8192
constexpr int L_W2  = 57344;   // [64][64]  = 8192
constexpr int L_WDEC= 65536;   // [16][64]  = 2048
constexpr int L_WEG = 67584;   // [64][32]  = 4096 (also zt f32[16][64] scratch)
constexpr int L_FB  = 71680;   // float[400] = 1600 (pad 1664)
constexpr int L_HA  = 73344;   // [16][72] bf16 = 2304
constexpr int L_HB  = 75648;   // 2304
constexpr int L_MS  = 77952;   // 2304
constexpr int L_AGG = 80256;   // [16][40] bf16 = 1280
constexpr int L_SL  = 81536;   // float[16]
constexpr int LDS_MEGA = 81600;  // <= 81920 -> 2 blocks/CU

#define DEVI __device__ __forceinline__

DEVI float bf2f(u16 u) {
    unsigned int v = ((unsigned int)u) << 16;
    float f; __builtin_memcpy(&f, &v, 4); return f;
}
DEVI u16 f2bf(float f) {   // round-to-nearest-even
    unsigned int v; __builtin_memcpy(&v, &f, 4);
    unsigned int r = (v + 0x7fffu + ((v >> 16) & 1u)) >> 16;
    return (u16)r;
}
DEVI float ldf(const void* p, size_t i, int f32) {
    return f32 ? ((const float*)p)[i] : bf2f(((const u16*)p)[i]);
}
DEVI float4 bf4(const u16* p) {
    ushort4 u = *reinterpret_cast<const ushort4*>(p);
    return make_float4(bf2f(u.x), bf2f(u.y), bf2f(u.z), bf2f(u.w));
}
DEVI float dot4(float4 a, float4 b) {
    return a.x*b.x + a.y*b.y + a.z*b.z + a.w*b.w;
}
DEVI float sigm(float v) { return 1.f / (1.f + __expf(-v)); }
DEVI float tanh_(float v) {
    float a = fabsf(v);
    float e = __expf(-2.f * a);
    float t = (1.f - e) / (1.f + e);
    return v < 0.f ? -t : t;
}

DEVI bfx8 frag8(const u16* p) { return *reinterpret_cast<const bfx8*>(p); }
DEVI fx4 splat4(float v) { fx4 r = {v, v, v, v}; return r; }
#define MFMA16(A, B, C) __builtin_amdgcn_mfma_f32_16x16x32_bf16((A), (B), (C), 0, 0, 0)

// transposed weight load: dst[o*64+k] = src[k*O+o]  (K = 64)
DEVI void loadT(u16* dst, const void* src, int O, int f32) {
    for (int i = threadIdx.x; i < 64 * O; i += 256) {
        int o = i >> 6, k = i & 63;
        dst[o * 64 + k] = f2bf(ldf(src, (size_t)k * O + o, f32));
    }
}
// transposed K-padded load: dst[64][32], src [16][64] (global f32/bf16)
DEVI void loadTpadG(u16* dst, const void* src, int f32) {
    for (int i = threadIdx.x; i < 64 * 32; i += 256) {
        int o = i >> 5, k = i & 31;
        dst[i] = (k < 16) ? f2bf(ldf(src, (size_t)k * 64 + o, f32)) : (u16)0;
    }
}
// same, src already bf16 [16][64]
DEVI void loadTpadB(u16* dst, const u16* src) {
    for (int i = threadIdx.x; i < 64 * 32; i += 256) {
        int o = i >> 5, k = i & 31;
        dst[i] = (k < 16) ? src[k * 64 + o] : (u16)0;
    }
}
DEVI void loadBias(float* dst, const void* src, int n, int f32) {
    for (int i = threadIdx.x; i < n; i += 256) dst[i] = ldf(src, i, f32);
}

// VALU gemm for the one-time domain MLP: weights pitch 64, acts pitch PH(72)
DEVI void gemm64v(const u16* WT, const u16* act, int l, int rb,
                  const float init[4], float out[4]) {
    const u16* w  = WT + l * 64;
    const u16* a0 = act + (rb +  0) * PH;
    const u16* a1 = act + (rb +  4) * PH;
    const u16* a2 = act + (rb +  8) * PH;
    const u16* a3 = act + (rb + 12) * PH;
    float o0 = init[0], o1 = init[1], o2 = init[2], o3 = init[3];
#pragma unroll 2
    for (int k4 = 0; k4 < 16; ++k4) {
        float4 wv4 = bf4(w + 4 * k4);
        o0 += dot4(bf4(a0 + 4 * k4), wv4);
        o1 += dot4(bf4(a1 + 4 * k4), wv4);
        o2 += dot4(bf4(a2 + 4 * k4), wv4);
        o3 += dot4(bf4(a3 + 4 * k4), wv4);
    }
    out[0] = o0; out[1] = o1; out[2] = o2; out[3] = o3;
}

// ---------------------------------------------------------------------------
// dtype detection (unchanged, verified)
// ---------------------------------------------------------------------------
__global__ void k_detect(const u16* __restrict__ x, int* __restrict__ flag) {
    __shared__ int cnt;
    if (threadIdx.x == 0) cnt = 0;
    __syncthreads();
    int local = 0;
#pragma unroll
    for (int j = 0; j < 4; ++j) {
        u16 u = x[threadIdx.x * 4 + j];
        int ex = (u >> 7) & 0xFF;
        if (ex >= 0x9A) ++local;
    }
    if (local) atomicAdd(&cnt, local);
    __syncthreads();
    if (threadIdx.x == 0) *flag = (cnt >= 8) ? 1 : 0;
}

// ---------------------------------------------------------------------------
// CSR build (unchanged, verified)
// ---------------------------------------------------------------------------
__global__ void k_count(const int* __restrict__ ei, const void* __restrict__ eattr,
                        const int* __restrict__ flag,
                        int* __restrict__ counts, float* __restrict__ S) {
    int f32 = *flag;
    int e = blockIdx.x * 256 + threadIdx.x;
    if (e < E_) {
        int dst = ei[E_ + e];
        atomicAdd(&counts[dst], 1);
        atomicAdd(&S[dst], ldf(eattr, e, f32));
    }
}

__global__ void k_scan(const int* __restrict__ counts, int* __restrict__ row_ptr,
                       int* __restrict__ cursor) {
    __shared__ int lds[256];
    int tid = threadIdx.x;
    int base = tid * 8, loc[8], s = 0;
#pragma unroll
    for (int i = 0; i < 8; ++i) { loc[i] = s; s += counts[base + i]; }
    lds[tid] = s; __syncthreads();
    for (int d = 1; d < 256; d <<= 1) {
        int v = (tid >= d) ? lds[tid - d] : 0;
        __syncthreads();
        lds[tid] += v;
        __syncthreads();
    }
    int off = (tid == 0) ? 0 : lds[tid - 1];
#pragma unroll
    for (int i = 0; i < 8; ++i) {
        int rp = off + loc[i];
        row_ptr[base + i] = rp; cursor[base + i] = rp;
    }
    if (tid == 255) row_ptr[V_] = lds[255];
}

__global__ void k_fill(const int* __restrict__ ei, const void* __restrict__ eattr,
                       const int* __restrict__ flag,
                       int* __restrict__ cursor, int* __restrict__ col_src,
                       float* __restrict__ col_att) {
    int f32 = *flag;
    int e = blockIdx.x * 256 + threadIdx.x;
    if (e < E_) {
        int dst = ei[E_ + e];
        int pos = atomicAdd(&cursor[dst], 1);
        col_src[pos] = ei[e];
        col_att[pos] = ldf(eattr, e, f32);
    }
}

// fused weights: W_egX = W_enc @ W_gX ; b_egX = b_enc @ W_gX (unchanged)
__global__ void k_wprep(const void* __restrict__ W_enc, const void* __restrict__ b_enc,
                        const void* __restrict__ W_gd, const void* __restrict__ W_gc,
                        const int* __restrict__ flag,
                        u16* __restrict__ wegA, u16* __restrict__ wegB,
                        float* __restrict__ begA, float* __restrict__ begB) {
    int f32 = *flag;
    int tid = threadIdx.x;
    for (int idx = tid; idx < 1024; idx += 256) {
        int c = idx >> 6, l = idx & 63;
        float sa = 0.f, sb = 0.f;
        for (int k = 0; k < 64; ++k) {
            float we = ldf(W_enc, c * 64 + k, f32);
            sa += we * ldf(W_gd, k * 64 + l, f32);
            sb += we * ldf(W_gc, k * 64 + l, f32);
        }
        wegA[idx] = f2bf(sa); wegB[idx] = f2bf(sb);
    }
    if (tid < 64) {
        float sa = 0.f, sb = 0.f;
        for (int k = 0; k < 64; ++k) {
            float be = ldf(b_enc, k, f32);
            sa += be * ldf(W_gd, k * 64 + tid, f32);
            sb += be * ldf(W_gc, k * 64 + tid, f32);
        }
        begA[tid] = sa; begB[tid] = sb;
    }
}

// ---------------------------------------------------------------------------
// pre-aggregation (unchanged, verified)
// ---------------------------------------------------------------------------
__global__ __launch_bounds__(256) void k_agg(
    const void* __restrict__ x, const int* __restrict__ flag,
    const int* __restrict__ row_ptr,
    const int* __restrict__ col_src, const float* __restrict__ col_att,
    u16* __restrict__ aggT) {
    __shared__ float lbuf[4 * CT_];   // 38,400 B
    int f32 = *flag;
    int tid = threadIdx.x;
    int n  = blockIdx.x >> 9;
    int v0 = (blockIdx.x & 511) * 4;
    for (int d = 0; d < 4; ++d) {
        int v = v0 + d;
        int e0 = row_ptr[v], e1 = row_ptr[v + 1];
        float acc[10];
#pragma unroll
        for (int k = 0; k < 10; ++k) acc[k] = 0.f;
        for (int e = e0; e < e1; ++e) {
            float a = col_att[e];
            size_t ro = (size_t)(n * V_ + col_src[e]) * CT_;
            if (f32) {
                const float* xr = (const float*)x + ro;
#pragma unroll
                for (int k = 0; k < 10; ++k) {
                    int idx = tid + 256 * k;
                    if (idx < CT_) acc[k] += a * xr[idx];
                }
            } else {
                const u16* xr = (const u16*)x + ro;
#pragma unroll
                for (int k = 0; k < 10; ++k) {
                    int idx = tid + 256 * k;
                    if (idx < CT_) acc[k] += a * bf2f(xr[idx]);
                }
            }
        }
#pragma unroll
        for (int k = 0; k < 10; ++k) {
            int idx = tid + 256 * k;
            if (idx < CT_) lbuf[d * CT_ + idx] = acc[k];
        }
    }
    __syncthreads();
    for (int w = tid; w < 4 * CT_; w += 256) {
        int t = w >> 6, rem = w & 63, d = rem >> 4, c = rem & 15;
        aggT[((size_t)(t * N_ + n) * V_ + v0 + d) * C_ + c] =
            f2bf(lbuf[d * CT_ + c * T_ + t]);
    }
}

// ---------------------------------------------------------------------------
// mega kernel, MFMA edition. 16 rows/block, 4 waves; wave w owns the 16-col
// slice [16w,16w+16) of every GEMM output (C-layout). Maps per lane:
//   lo=lane&15, hi=lane>>4; A-frag row=lo, k=hi*8(+32*ks); C/D row=hi*4+q,
//   col=cc=16*wv+lo. Decode (cols 0..15) done by wave 3.
// ---------------------------------------------------------------------------
__global__ __launch_bounds__(256, 2) void k_mega(
    const void* __restrict__ x, const u16* __restrict__ aggT,
    const float* __restrict__ Sg, const int* __restrict__ flag,
    const void* __restrict__ W_enc, const void* __restrict__ b_enc,
    const void* __restrict__ gd_Wi, const void* __restrict__ gd_Wh, const void* __restrict__ gd_b,
    const void* __restrict__ W_dom1, const void* __restrict__ b_dom1,
    const void* __restrict__ W_dom2, const void* __restrict__ b_dom2,
    const void* __restrict__ ode_W1, const void* __restrict__ ode_b1,
    const void* __restrict__ ode_W2, const void* __restrict__ ode_b2,
    const void* __restrict__ gc_Wi, const void* __restrict__ gc_Wh, const void* __restrict__ gc_b,
    const void* __restrict__ W_dec, const void* __restrict__ b_dec,
    const u16* __restrict__ wegA, const u16* __restrict__ wegB,
    const float* __restrict__ begA, const float* __restrict__ begB,
    void* __restrict__ outp, int staged) {
    extern __shared__ char smem[];
    u16* WiT = (u16*)(smem + L_WIT);
    u16* WhT = (u16*)(smem + L_WHT);
    u16* W1H = (u16*)(smem + L_W1H);
    u16* W2T = (u16*)(smem + L_W2);
    u16* WdT = (u16*)(smem + L_WDEC);
    u16* WgT = (u16*)(smem + L_WEG);      // Weg / WencT / zt f32 scratch
    float* fB = (float*)(smem + L_FB);
    u16* hA  = (u16*)(smem + L_HA);
    u16* hB  = (u16*)(smem + L_HB);
    u16* mS  = (u16*)(smem + L_MS);
    u16* agS = (u16*)(smem + L_AGG);
    float* Sl = (float*)(smem + L_SL);

    const int f32 = *flag;
    const int tid = threadIdx.x;
    const int lid = tid & 63, wv = tid >> 6;
    const int lo = lid & 15, hi = lid >> 4;
    const int cc = wv * 16 + lo;          // C-layout column for this lane
    const int sr = tid >> 4, sc = tid & 15;  // staging map (16x16)
    const int base = blockIdx.x * 16;
    const int n = base >> 11, v0 = base & 2047;
    const u16* aggP = aggT + ((size_t)n * V_ + v0) * C_ + tid;

    // ---- phase A setup -----------------------------------------------------
    loadT(WiT, gd_Wi, 192, f32);
    loadT(WhT, gd_Wh, 192, f32);
    loadTpadB(WgT, wegA);
    loadBias(fB, gd_b, 192, f32);
    loadBias(fB + 192, begA, 64, 1);
    if (tid < 16) Sl[tid] = Sg[v0 + tid];
    for (int i = tid; i < 16 * PH; i += 256) hA[i] = 0;          // h(-1) = 0
    { int r = tid >> 4, k = 16 + (tid & 15); agS[r * PA + k] = 0; } // K-pad zeros
    agS[sr * PA + sc] = aggP[0];                                  // stage t=0
    u16 pf = aggP[AGST];                                          // t=1
    __syncthreads();

    // hoist Wi-gate + Weg B-frags (loop-invariant, 28 VGPR)
    bfx8 fWz0 = frag8(WiT + (  0 + cc) * 64 +      hi * 8);
    bfx8 fWz1 = frag8(WiT + (  0 + cc) * 64 + 32 + hi * 8);
    bfx8 fWr0 = frag8(WiT + ( 64 + cc) * 64 +      hi * 8);
    bfx8 fWr1 = frag8(WiT + ( 64 + cc) * 64 + 32 + hi * 8);
    bfx8 fWn0 = frag8(WiT + (128 + cc) * 64 +      hi * 8);
    bfx8 fWn1 = frag8(WiT + (128 + cc) * 64 + 32 + hi * 8);
    bfx8 fWg  = frag8(WgT + cc * 32 + hi * 8);
    float bz = fB[cc], br = fB[64 + cc], bn = fB[128 + cc], bgv = fB[192 + cc];
    float Sv[4];
#pragma unroll
    for (int q = 0; q < 4; ++q) Sv[q] = Sl[hi * 4 + q];

    float hd[4] = {0.f, 0.f, 0.f, 0.f};
    u16 *hR = hA, *hW = hB;
    for (int t = 0; t < T_; ++t) {
        // s3: m = agg @ W_egA + S*beg  -> mS
        fx4 ma;
#pragma unroll
        for (int q = 0; q < 4; ++q) ma[q] = Sv[q] * bgv;
        ma = MFMA16(frag8(agS + lo * PA + hi * 8), fWg, ma);
#pragma unroll
        for (int q = 0; q < 4; ++q) mS[(hi * 4 + q) * PH + cc] = f2bf(ma[q]);
        __syncthreads();
        // s4: stage agg(t+1); GRU(m, hd)
        agS[sr * PA + sc] = pf;
        pf = (t + 2 < T_) ? aggP[(size_t)(t + 2) * AGST] : pf;
        bfx8 m0 = frag8(mS + lo * PH +      hi * 8);
        bfx8 m1 = frag8(mS + lo * PH + 32 + hi * 8);
        bfx8 a0 = frag8(hR + lo * PH +      hi * 8);
        bfx8 a1 = frag8(hR + lo * PH + 32 + hi * 8);
        fx4 az = splat4(bz); az = MFMA16(m0, fWz0, az); az = MFMA16(m1, fWz1, az);
        fx4 ar = splat4(br); ar = MFMA16(m0, fWr0, ar); ar = MFMA16(m1, fWr1, ar);
        fx4 an = splat4(bn); an = MFMA16(m0, fWn0, an); an = MFMA16(m1, fWn1, an);
        fx4 gz = splat4(0.f), gr = splat4(0.f), gn = splat4(0.f);
        gz = MFMA16(a0, frag8(WhT + (  0 + cc) * 64 +      hi * 8), gz);
        gz = MFMA16(a1, frag8(WhT + (  0 + cc) * 64 + 32 + hi * 8), gz);
        gr = MFMA16(a0, frag8(WhT + ( 64 + cc) * 64 +      hi * 8), gr);
        gr = MFMA16(a1, frag8(WhT + ( 64 + cc) * 64 + 32 + hi * 8), gr);
        gn = MFMA16(a0, frag8(WhT + (128 + cc) * 64 +      hi * 8), gn);
        gn = MFMA16(a1, frag8(WhT + (128 + cc) * 64 + 32 + hi * 8), gn);
#pragma unroll
        for (int q = 0; q < 4; ++q) {
            float z = sigm(az[q] + gz[q]);
            float r = sigm(ar[q] + gr[q]);
            float nn = tanh_(an[q] + r * gn[q]);
            hd[q] = (1.f - z) * nn + z * hd[q];
            hW[(hi * 4 + q) * PH + cc] = f2bf(hd[q]);
        }
        __syncthreads();
        u16* tp = hR; hR = hW; hW = tp;
    }

    // ---- domain MLP (one-time, VALU path; old thread map l=lid, rb=wv) -----
#pragma unroll
    for (int q = 0; q < 4; ++q) hA[(hi * 4 + q) * PH + cc] = f2bf(hd[q]);
    loadT(W1H, W_dom1, 64, f32);
    loadT(W2T, W_dom2, 64, f32);
    loadT(WiT, (const void*)((const char*)ode_W1 + (size_t)64 * 64 * (f32 ? 4 : 2)),
          64, f32);   // zD half of ode_W1
    loadBias(fB, b_dom1, 64, f32);
    loadBias(fB + 64, b_dom2, 64, f32);
    loadBias(fB + 128, ode_b1, 64, f32);
    __syncthreads();
    float init4[4], tmp4[4];
#pragma unroll
    for (int j = 0; j < 4; ++j) init4[j] = fB[lid];
    gemm64v(W1H, hA, lid, wv, init4, tmp4);
#pragma unroll
    for (int j = 0; j < 4; ++j) mS[(wv + 4 * j) * PH + lid] = f2bf(tanh_(tmp4[j]));
    __syncthreads();
    float zD4[4];
#pragma unroll
    for (int j = 0; j < 4; ++j) init4[j] = fB[64 + lid];
    gemm64v(W2T, mS, lid, wv, init4, zD4);
    __syncthreads();
#pragma unroll
    for (int j = 0; j < 4; ++j) hA[(wv + 4 * j) * PH + lid] = f2bf(zD4[j]);
    __syncthreads();
    float zt4[4];
#pragma unroll
    for (int j = 0; j < 4; ++j) init4[j] = fB[128 + lid];
    gemm64v(WiT, hA, lid, wv, init4, zt4);
    {
        float* ztS = (float*)WgT;
#pragma unroll
        for (int j = 0; j < 4; ++j) ztS[(wv + 4 * j) * 64 + lid] = zt4[j];
    }
    __syncthreads();
    float ztv[4];
    {
        const float* ztS = (const float*)WgT;
#pragma unroll
        for (int q = 0; q < 4; ++q) ztv[q] = ztS[(hi * 4 + q) * 64 + cc];
    }
    __syncthreads();   // everyone read zt before WgT is overwritten

    // ---- phase B setup -----------------------------------------------------
    loadT(WiT, gc_Wi, 192, f32);
    loadT(WhT, gc_Wh, 192, f32);
    loadT(W1H, ode_W1, 64, f32);           // h half
    loadT(W2T, ode_W2, 64, f32);
    loadT(WdT, W_dec, 16, f32);
    loadTpadG(WgT, W_enc, f32);            // W_enc^T (for h0)
    loadBias(fB, gc_b, 192, f32);
    loadBias(fB + 192, begB, 64, 1);
    loadBias(fB + 256, ode_b2, 64, f32);
    loadBias(fB + 320, b_dec, 16, f32);
    loadBias(fB + 336, b_enc, 64, f32);
    agS[sr * PA + sc] = f2bf(ldf(x, (size_t)(base + sr) * CT_ + (size_t)sc * T_, f32));
    __syncthreads();
    // h0 = x[:,:,:,0] @ W_enc + b_enc
    float h[4];
    {
        fx4 ha = splat4(fB[336 + cc]);
        ha = MFMA16(frag8(agS + lo * PA + hi * 8), frag8(WgT + cc * 32 + hi * 8), ha);
#pragma unroll
        for (int q = 0; q < 4; ++q) { h[q] = ha[q]; hB[(hi * 4 + q) * PH + cc] = f2bf(ha[q]); }
    }
    __syncthreads();
    // decode(0) by wave 3; meanwhile load wegB + stage agg(1)
    float bdv = fB[320 + lo];
    if (wv == 3) {
        fx4 da = splat4(bdv);
        da = MFMA16(frag8(hB + lo * PH +      hi * 8), frag8(WdT + lo * 64 +      hi * 8), da);
        da = MFMA16(frag8(hB + lo * PH + 32 + hi * 8), frag8(WdT + lo * 64 + 32 + hi * 8), da);
        if (staged) {
#pragma unroll
            for (int q = 0; q < 4; ++q)
                ((u16*)outp)[((size_t)0 * NV_ + base + hi * 4 + q) * C_ + lo] = f2bf(da[q]);
        } else {
#pragma unroll
            for (int q = 0; q < 4; ++q) {
                size_t off = (size_t)(base + hi * 4 + q) * CT_ + (size_t)lo * T_ + 0;
                if (f32) ((float*)outp)[off] = da[q]; else ((u16*)outp)[off] = f2bf(da[q]);
            }
        }
    }
    loadTpadB(WgT, wegB);
    agS[sr * PA + sc] = aggP[AGST];       // stage t=1
    pf = aggP[(size_t)2 * AGST];          // t=2
    __syncthreads();

    // hoist gc frags
    fWz0 = frag8(WiT + (  0 + cc) * 64 +      hi * 8);
    fWz1 = frag8(WiT + (  0 + cc) * 64 + 32 + hi * 8);
    fWr0 = frag8(WiT + ( 64 + cc) * 64 +      hi * 8);
    fWr1 = frag8(WiT + ( 64 + cc) * 64 + 32 + hi * 8);
    fWn0 = frag8(WiT + (128 + cc) * 64 +      hi * 8);
    fWn1 = frag8(WiT + (128 + cc) * 64 + 32 + hi * 8);
    fWg  = frag8(WgT + cc * 32 + hi * 8);
    bz = fB[cc]; br = fB[64 + cc]; bn = fB[128 + cc]; bgv = fB[192 + cc];
    float b2v = fB[256 + cc];

    for (int t = 1; t < T_; ++t) {
        // s1: u = tanh(h @ ode_W1h + zt) -> mS
        fx4 ua = {ztv[0], ztv[1], ztv[2], ztv[3]};
        ua = MFMA16(frag8(hB + lo * PH +      hi * 8), frag8(W1H + cc * 64 +      hi * 8), ua);
        ua = MFMA16(frag8(hB + lo * PH + 32 + hi * 8), frag8(W1H + cc * 64 + 32 + hi * 8), ua);
#pragma unroll
        for (int q = 0; q < 4; ++q) mS[(hi * 4 + q) * PH + cc] = f2bf(tanh_(ua[q]));
        __syncthreads();
        // s2: dh = u @ ode_W2 + b2 ; ho = h + dh -> hA
        fx4 da = splat4(b2v);
        da = MFMA16(frag8(mS + lo * PH +      hi * 8), frag8(W2T + cc * 64 +      hi * 8), da);
        da = MFMA16(frag8(mS + lo * PH + 32 + hi * 8), frag8(W2T + cc * 64 + 32 + hi * 8), da);
        float ho[4];
#pragma unroll
        for (int q = 0; q < 4; ++q) {
            ho[q] = h[q] + da[q];
            hA[(hi * 4 + q) * PH + cc] = f2bf(ho[q]);
        }
        __syncthreads();
        // s3: m = agg @ W_egB + S*beg -> mS
        fx4 ma;
#pragma unroll
        for (int q = 0; q < 4; ++q) ma[q] = Sv[q] * bgv;
        ma = MFMA16(frag8(agS + lo * PA + hi * 8), fWg, ma);
#pragma unroll
        for (int q = 0; q < 4; ++q) mS[(hi * 4 + q) * PH + cc] = f2bf(ma[q]);
        __syncthreads();
        // s4: stage agg(t+1); GRU(m, ho) -> h -> hB
        agS[sr * PA + sc] = pf;
        pf = (t + 2 < T_) ? aggP[(size_t)(t + 2) * AGST] : pf;
        bfx8 m0 = frag8(mS + lo * PH +      hi * 8);
        bfx8 m1 = frag8(mS + lo * PH + 32 + hi * 8);
        bfx8 a0 = frag8(hA + lo * PH +      hi * 8);
        bfx8 a1 = frag8(hA + lo * PH + 32 + hi * 8);
        fx4 az = splat4(bz); az = MFMA16(m0, fWz0, az); az = MFMA16(m1, fWz1, az);
        fx4 ar = splat4(br); ar = MFMA16(m0, fWr0, ar); ar = MFMA16(m1, fWr1, ar);
        fx4 an = splat4(bn); an = MFMA16(m0, fWn0, an); an = MFMA16(m1, fWn1, an);
        fx4 gz = splat4(0.f), gr = splat4(0.f), gn = splat4(0.f);
        gz = MFMA16(a0, frag8(WhT + (  0 + cc) * 64 +      hi * 8), gz);
        gz = MFMA16(a1, frag8(WhT + (  0 + cc) * 64 + 32 + hi * 8), gz);
        gr = MFMA16(a0, frag8(WhT + ( 64 + cc) * 64 +      hi * 8), gr);
        gr = MFMA16(a1, frag8(WhT + ( 64 + cc) * 64 + 32 + hi * 8), gr);
        gn = MFMA16(a0, frag8(WhT + (128 + cc) * 64 +      hi * 8), gn);
        gn = MFMA16(a1, frag8(WhT + (128 + cc) * 64 + 32 + hi * 8), gn);
#pragma unroll
        for (int q = 0; q < 4; ++q) {
            float z = sigm(az[q] + gz[q]);
            float r = sigm(ar[q] + gr[q]);
            float nn = tanh_(an[q] + r * gn[q]);
            h[q] = (1.f - z) * nn + z * ho[q];
            hB[(hi * 4 + q) * PH + cc] = f2bf(h[q]);
        }
        __syncthreads();
        // decode(t) by wave 3 (overlaps other waves' next s1)
        if (wv == 3) {
            fx4 dd = splat4(bdv);
            dd = MFMA16(frag8(hB + lo * PH +      hi * 8), frag8(WdT + lo * 64 +      hi * 8), dd);
            dd = MFMA16(frag8(hB + lo * PH + 32 + hi * 8), frag8(WdT + lo * 64 + 32 + hi * 8), dd);
            if (staged) {
#pragma unroll
                for (int q = 0; q < 4; ++q)
                    ((u16*)outp)[((size_t)t * NV_ + base + hi * 4 + q) * C_ + lo] = f2bf(dd[q]);
            } else {
#pragma unroll
                for (int q = 0; q < 4; ++q) {
                    size_t off = (size_t)(base + hi * 4 + q) * CT_ + (size_t)lo * T_ + t;
                    if (f32) ((float*)outp)[off] = dd[q]; else ((u16*)outp)[off] = f2bf(dd[q]);
                }
            }
        }
    }
}

// de-transpose staged output [t][row][c] -> d_out [row][c][t] (unchanged)
__global__ __launch_bounds__(256) void k_detrans(const u16* __restrict__ stage,
                                                 const int* __restrict__ flag,
                                                 void* __restrict__ out) {
    __shared__ u16 lt[8 * CT_];   // 38,400 B
    int f32 = *flag;
    int tid = threadIdx.x;
    int base = blockIdx.x * 8;
    int r = tid >> 4, c = tid & 15;
    for (int t = 0; t < T_; ++t) {
        if (tid < 128)
            lt[r * CT_ + c * T_ + t] = stage[((size_t)t * NV_ + base + r) * C_ + c];
    }
    __syncthreads();
    size_t ob = (size_t)base * CT_;
    if (f32) {
        float* o = (float*)out;
        for (int i = tid; i < 8 * CT_; i += 256) o[ob + i] = bf2f(lt[i]);
    } else {
        u16* o = (u16*)out;
        for (int i = tid; i < 8 * CT_; i += 256) o[ob + i] = lt[i];
    }
}

// ---------------------------------------------------------------------------
extern "C" void kernel_launch(void* const* d_in, const int* in_sizes, int n_in,
                              void* d_out, int out_size, void* d_ws, size_t ws_size,
                              hipStream_t stream) {
    const void* x      = d_in[0];
    const int*  ei     = (const int*)d_in[1];
    const void* eattr  = d_in[2];
    const void* W_enc  = d_in[3];
    const void* b_enc  = d_in[4];
    const void* W_gd   = d_in[5];
    const void* gd_Wi  = d_in[6];
    const void* gd_Wh  = d_in[7];
    const void* gd_b   = d_in[8];
    const void* W_dom1 = d_in[9];
    const void* b_dom1 = d_in[10];
    const void* W_dom2 = d_in[11];
    const void* b_dom2 = d_in[12];
    const void* ode_W1 = d_in[13];
    const void* ode_b1 = d_in[14];
    const void* ode_W2 = d_in[15];
    const void* ode_b2 = d_in[16];
    const void* W_gc   = d_in[17];
    const void* gc_Wi  = d_in[18];
    const void* gc_Wh  = d_in[19];
    const void* gc_b   = d_in[20];
    const void* W_dec  = d_in[21];
    const void* b_dec  = d_in[22];

    char* ws = (char*)d_ws;
    u16*   aggT    = (u16*)  (ws + OFF_AGGT);
    int*   counts  = (int*)  (ws + OFF_COUNTS);
    float* S       = (float*)(ws + OFF_S);
    int*   row_ptr = (int*)  (ws + OFF_RP);
    int*   cursor  = (int*)  (ws + OFF_CUR);
    int*   col_src = (int*)  (ws + OFF_CSRC);
    float* col_att = (float*)(ws + OFF_CATT);
    u16*   wegA    = (u16*)  (ws + OFF_WEGA);
    u16*   wegB    = (u16*)  (ws + OFF_WEGB);
    float* begA    = (float*)(ws + OFF_BEGA);
    float* begB    = (float*)(ws + OFF_BEGB);
    int*   flag    = (int*)  (ws + OFF_FLAG);
    u16*   stage   = (u16*)  (ws + OFF_STAGE);

    int staged = (ws_size >= NEED_STAGE) ? 1 : 0;
    void* mega_out = staged ? (void*)stage : d_out;

    (void)hipFuncSetAttribute((const void*)k_mega,
                              hipFuncAttributeMaxDynamicSharedMemorySize, LDS_MEGA);

    hipLaunchKernelGGL(k_detect, dim3(1), dim3(256), 0, stream, (const u16*)x, flag);
    hipMemsetAsync(ws + OFF_COUNTS, 0, 16384, stream);  // counts + S
    hipLaunchKernelGGL(k_count, dim3(E_ / 256), dim3(256), 0, stream,
                       ei, eattr, flag, counts, S);
    hipLaunchKernelGGL(k_scan, dim3(1), dim3(256), 0, stream,
                       counts, row_ptr, cursor);
    hipLaunchKernelGGL(k_fill, dim3(E_ / 256), dim3(256), 0, stream,
                       ei, eattr, flag, cursor, col_src, col_att);
    hipLaunchKernelGGL(k_wprep, dim3(1), dim3(256), 0, stream,
                       W_enc, b_enc, W_gd, W_gc, flag, wegA, wegB, begA, begB);
    hipLaunchKernelGGL(k_agg, dim3(N_ * V_ / 4), dim3(256), 0, stream,
                       x, flag, row_ptr, col_src, col_att, aggT);
    hipLaunchKernelGGL(k_mega, dim3(NV_ / 16), dim3(256), LDS_MEGA, stream,
                       x, aggT, S, flag, W_enc, b_enc, gd_Wi, gd_Wh, gd_b,
                       W_dom1, b_dom1, W_dom2, b_dom2,
                       ode_W1, ode_b1, ode_W2, ode_b2,
                       gc_Wi, gc_Wh, gc_b, W_dec, b_dec,
                       wegA, wegB, begA, begB, mega_out, staged);
    if (staged)
        hipLaunchKernelGGL(k_detrans, dim3(NV_ / 8), dim3(256), 0, stream,
                           stage, flag, d_out);
}